// Round 3
// baseline (2923.687 us; speedup 1.0000x reference)
//
#include <hip/hip_runtime.h>

// ---------------------------------------------------------------------------
// EdgeGatedConv — bf16 MFMA, no-LDS B (L2-direct), fused edge pipeline.
//   prep: pack W_line/W_gate/W_atom to bf16 fragment layout in d_ws
//   K0 k_count:     cnt[dst]++ (scatter-mean denominator)
//   K1 k_line_mfma: msg = silu([lg_x[src],lg_x[dst],lg_ea]@W_line+b) -> atomic out_lg[dst]
//   K2 k_edge_fused: lnew = lg_x + acc/max(cnt,1)  (write out_lg)
//                    enew = LN(edge_attr + lnew)    (write out_edge, in-register LN)
//                    gate = sigmoid(enew@W_gate+b); atomic gate*enew -> out_x[col]
//   K3 k_atom_mfma: h = silu([x,agg]@W_atom+b); out_x = LN(x+h)
//
// MFMA 16x16x32 bf16: A row = lane&15, B col = lane&15, k-slice = (lane>>4)*8+j
// on BOTH operands (consistent bijection). C/D: col = lane&15, row=(lane>>4)*4+reg.
// ---------------------------------------------------------------------------

typedef __attribute__((ext_vector_type(8))) short s16x8;
typedef __attribute__((ext_vector_type(4))) float f32x4;

__device__ __forceinline__ short f2bf(float f) {
    unsigned u = __float_as_uint(f);
    u += 0x7FFF + ((u >> 16) & 1);           // round-to-nearest-even
    return (short)(u >> 16);
}

__device__ __forceinline__ s16x8 pack8(const float* v) {
    s16x8 r;
    #pragma unroll
    for (int j = 0; j < 8; ++j) r[j] = f2bf(v[j]);
    return r;
}

// pack W[K][128] -> chunks: chunk c = g*128+col (g = k/8) holds W[g*8+j][col], j=0..7
__global__ __launch_bounds__(256) void k_pack(const float* __restrict__ W,
                                              short* __restrict__ P, int nchunk) {
    int c = blockIdx.x * 256 + threadIdx.x;
    if (c >= nchunk) return;
    int g = c >> 7, col = c & 127, k0 = g * 8;
    s16x8 v;
    #pragma unroll
    for (int j = 0; j < 8; ++j) v[j] = f2bf(W[(size_t)(k0 + j) * 128 + col]);
    ((s16x8*)P)[c] = v;
}

__global__ __launch_bounds__(256) void k_count(const int* __restrict__ dst,
                                               float* __restrict__ cnt, int n) {
    int i = blockIdx.x * 256 + threadIdx.x;
    if (i < n) atomicAdd(&cnt[dst[i]], 1.f);
}

// ---------------- K1: line-graph message GEMM + scatter (no LDS) ----------------
__global__ __launch_bounds__(256) void k_line_mfma(
    const float* __restrict__ lg_x, const float* __restrict__ lg_ea,
    const short* __restrict__ Wp, const float* __restrict__ W_line,
    const float* __restrict__ b_line,
    const int* __restrict__ lg_src, const int* __restrict__ lg_dst,
    float* __restrict__ lgacc, int LEn)
{
    const int tid = threadIdx.x;
    const int ln = tid & 63, wv = tid >> 6;
    const int l15 = ln & 15, lhi = ln >> 4;
    const int eb = blockIdx.x * 128 + wv * 32;
    const s16x8* Bv = (const s16x8*)Wp;

    const float *sp[2], *dp[2];
    #pragma unroll
    for (int mt = 0; mt < 2; ++mt) {
        int e = eb + mt * 16 + l15;
        int ec = e < LEn ? e : LEn - 1;
        sp[mt] = lg_x + (size_t)lg_src[ec] * 128;
        dp[mt] = lg_x + (size_t)lg_dst[ec] * 128;
    }

    f32x4 acc[2][8];
    #pragma unroll
    for (int m = 0; m < 2; ++m)
        #pragma unroll
        for (int n = 0; n < 8; ++n) acc[m][n] = (f32x4){0.f, 0.f, 0.f, 0.f};

    #pragma unroll 2
    for (int kt = 0; kt < 8; ++kt) {
        int ko = (kt & 3) * 32 + lhi * 8;
        s16x8 a[2];
        #pragma unroll
        for (int mt = 0; mt < 2; ++mt) {
            const float* p = ((kt < 4) ? sp[mt] : dp[mt]) + ko;
            float buf[8];
            *(float4*)&buf[0] = *(const float4*)p;
            *(float4*)&buf[4] = *(const float4*)(p + 4);
            a[mt] = pack8(buf);
        }
        const s16x8* brow = Bv + (size_t)(kt * 4 + lhi) * 128 + l15;
        #pragma unroll
        for (int nt = 0; nt < 8; ++nt) {
            s16x8 b = brow[nt * 16];
            acc[0][nt] = __builtin_amdgcn_mfma_f32_16x16x32_bf16(a[0], b, acc[0][nt], 0, 0, 0);
            acc[1][nt] = __builtin_amdgcn_mfma_f32_16x16x32_bf16(a[1], b, acc[1][nt], 0, 0, 0);
        }
    }

    #pragma unroll
    for (int nt = 0; nt < 8; ++nt) {
        int col = nt * 16 + l15;
        float wl = W_line[(size_t)256 * 128 + col];
        float bs = b_line[col];
        #pragma unroll
        for (int mt = 0; mt < 2; ++mt)
            #pragma unroll
            for (int r = 0; r < 4; ++r) {
                int e = eb + mt * 16 + lhi * 4 + r;
                if (e < LEn) {
                    float v = acc[mt][nt][r] + bs + wl * lg_ea[e];
                    float s = v / (1.f + __expf(-v));
                    atomicAdd(&lgacc[(size_t)lg_dst[e] * 128 + col], s);
                }
            }
    }
}

// ---------------- K2: fused lg-finalize + edge LN + gate GEMM + scatter ----------------
__global__ __launch_bounds__(256) void k_edge_fused(
    const float* __restrict__ lg_x, const float* __restrict__ edge_attr,
    const float* __restrict__ cnt,
    const float* __restrict__ g_edge, const float* __restrict__ beta_edge,
    const short* __restrict__ Wp, const float* __restrict__ bg,
    const int* __restrict__ colidx,
    float* __restrict__ out_lg, float* __restrict__ out_edge,
    float* __restrict__ agg, int En)
{
    const int tid = threadIdx.x;
    const int ln = tid & 63, wv = tid >> 6;
    const int l15 = ln & 15, lhi = ln >> 4;
    const int eb = blockIdx.x * 128 + wv * 32;
    const s16x8* Bv = (const s16x8*)Wp;

    s16x8 afrag[2][4];
    #pragma unroll
    for (int mt = 0; mt < 2; ++mt) {
        int e = eb + mt * 16 + l15;
        int ec = e < En ? e : En - 1;
        const size_t rb = (size_t)ec * 128;
        const float inv = 1.f / fmaxf(cnt[ec], 1.f);
        float t[4][8];
        float s = 0.f, sq = 0.f;
        #pragma unroll
        for (int kt = 0; kt < 4; ++kt) {
            int ko = kt * 32 + lhi * 8;
            float la[8], lx[8], le[8], lnew[8];
            *(float4*)&la[0] = *(const float4*)&out_lg[rb + ko];
            *(float4*)&la[4] = *(const float4*)&out_lg[rb + ko + 4];
            *(float4*)&lx[0] = *(const float4*)&lg_x[rb + ko];
            *(float4*)&lx[4] = *(const float4*)&lg_x[rb + ko + 4];
            *(float4*)&le[0] = *(const float4*)&edge_attr[rb + ko];
            *(float4*)&le[4] = *(const float4*)&edge_attr[rb + ko + 4];
            #pragma unroll
            for (int j = 0; j < 8; ++j) {
                lnew[j] = fmaf(la[j], inv, lx[j]);
                float tv = le[j] + lnew[j];
                t[kt][j] = tv;
                s += tv; sq += tv * tv;
            }
            if (e < En) {
                *(float4*)&out_lg[rb + ko]     = *(float4*)&lnew[0];
                *(float4*)&out_lg[rb + ko + 4] = *(float4*)&lnew[4];
            }
        }
        // reduce across the 4 lanes (lhi 0..3) holding this row
        s  += __shfl_xor(s, 16);  sq += __shfl_xor(sq, 16);
        s  += __shfl_xor(s, 32);  sq += __shfl_xor(sq, 32);
        float mean = s * (1.f / 128.f);
        float var  = sq * (1.f / 128.f) - mean * mean;
        float rstd = rsqrtf(var + 1e-5f);
        #pragma unroll
        for (int kt = 0; kt < 4; ++kt) {
            int ko = kt * 32 + lhi * 8;
            float gg[8], bb[8], en[8];
            *(float4*)&gg[0] = *(const float4*)&g_edge[ko];
            *(float4*)&gg[4] = *(const float4*)&g_edge[ko + 4];
            *(float4*)&bb[0] = *(const float4*)&beta_edge[ko];
            *(float4*)&bb[4] = *(const float4*)&beta_edge[ko + 4];
            #pragma unroll
            for (int j = 0; j < 8; ++j)
                en[j] = fmaf((t[kt][j] - mean) * rstd, gg[j], bb[j]);
            if (e < En) {
                *(float4*)&out_edge[rb + ko]     = *(float4*)&en[0];
                *(float4*)&out_edge[rb + ko + 4] = *(float4*)&en[4];
            }
            afrag[mt][kt] = pack8(en);
        }
    }

    f32x4 acc[2][8];
    #pragma unroll
    for (int m = 0; m < 2; ++m)
        #pragma unroll
        for (int n = 0; n < 8; ++n) acc[m][n] = (f32x4){0.f, 0.f, 0.f, 0.f};

    #pragma unroll
    for (int kt = 0; kt < 4; ++kt) {
        const s16x8* brow = Bv + (size_t)(kt * 4 + lhi) * 128 + l15;
        #pragma unroll
        for (int nt = 0; nt < 8; ++nt) {
            s16x8 b = brow[nt * 16];
            acc[0][nt] = __builtin_amdgcn_mfma_f32_16x16x32_bf16(afrag[0][kt], b, acc[0][nt], 0, 0, 0);
            acc[1][nt] = __builtin_amdgcn_mfma_f32_16x16x32_bf16(afrag[1][kt], b, acc[1][nt], 0, 0, 0);
        }
    }

    #pragma unroll
    for (int nt = 0; nt < 8; ++nt) {
        int col = nt * 16 + l15;
        float bs = bg[col];
        #pragma unroll
        for (int mt = 0; mt < 2; ++mt)
            #pragma unroll
            for (int r = 0; r < 4; ++r) {
                int e = eb + mt * 16 + lhi * 4 + r;
                if (e < En) {
                    float g = 1.f / (1.f + __expf(-(acc[mt][nt][r] + bs)));
                    float val = g * out_edge[(size_t)e * 128 + col];
                    atomicAdd(&agg[(size_t)colidx[e] * 128 + col], val);
                }
            }
    }
}

// ---------------- K3: atom GEMM + residual + in-register LayerNorm (no LDS) ----------------
__global__ __launch_bounds__(256) void k_atom_mfma(
    const float* __restrict__ x, const float* __restrict__ aggin,
    const short* __restrict__ Wp, const float* __restrict__ ba,
    const float* __restrict__ gn, const float* __restrict__ bn,
    float* __restrict__ out, int Nn)
{
    const int tid = threadIdx.x;
    const int ln = tid & 63, wv = tid >> 6;
    const int l15 = ln & 15, lhi = ln >> 4;
    const int nb = blockIdx.x * 128 + wv * 32;
    const s16x8* Bv = (const s16x8*)Wp;

    const float *xp[2], *ap[2];
    #pragma unroll
    for (int mt = 0; mt < 2; ++mt) {
        int n = nb + mt * 16 + l15;
        size_t nc = (size_t)(n < Nn ? n : Nn - 1) * 128;
        xp[mt] = x + nc;
        ap[mt] = aggin + nc;
    }

    f32x4 acc[2][8];
    #pragma unroll
    for (int m = 0; m < 2; ++m)
        #pragma unroll
        for (int n = 0; n < 8; ++n) acc[m][n] = (f32x4){0.f, 0.f, 0.f, 0.f};

    #pragma unroll 2
    for (int kt = 0; kt < 8; ++kt) {
        int ko = (kt & 3) * 32 + lhi * 8;
        s16x8 a[2];
        #pragma unroll
        for (int mt = 0; mt < 2; ++mt) {
            const float* p = ((kt < 4) ? xp[mt] : ap[mt]) + ko;
            float buf[8];
            *(float4*)&buf[0] = *(const float4*)p;
            *(float4*)&buf[4] = *(const float4*)(p + 4);
            a[mt] = pack8(buf);
        }
        const s16x8* brow = Bv + (size_t)(kt * 4 + lhi) * 128 + l15;
        #pragma unroll
        for (int nt = 0; nt < 8; ++nt) {
            s16x8 b = brow[nt * 16];
            acc[0][nt] = __builtin_amdgcn_mfma_f32_16x16x32_bf16(a[0], b, acc[0][nt], 0, 0, 0);
            acc[1][nt] = __builtin_amdgcn_mfma_f32_16x16x32_bf16(a[1], b, acc[1][nt], 0, 0, 0);
        }
    }

    // t = x + silu(acc + ba), then in-register LN over 16-lane row groups
    #pragma unroll
    for (int mt = 0; mt < 2; ++mt)
        #pragma unroll
        for (int r = 0; r < 4; ++r) {
            int n = nb + mt * 16 + lhi * 4 + r;
            size_t nr = (size_t)(n < Nn ? n : 0) * 128;
            float s = 0.f, sq = 0.f;
            #pragma unroll
            for (int nt = 0; nt < 8; ++nt) {
                int col = nt * 16 + l15;
                float v = acc[mt][nt][r] + ba[col];
                float h = v / (1.f + __expf(-v));
                float t = x[nr + col] + h;
                acc[mt][nt][r] = t;
                s += t; sq += t * t;
            }
            #pragma unroll
            for (int off = 8; off; off >>= 1) {
                s  += __shfl_xor(s, off);
                sq += __shfl_xor(sq, off);
            }
            float mean = s * (1.f / 128.f);
            float var  = sq * (1.f / 128.f) - mean * mean;
            float rstd = rsqrtf(var + 1e-5f);
            if (n < Nn) {
                #pragma unroll
                for (int nt = 0; nt < 8; ++nt) {
                    int col = nt * 16 + l15;
                    float o = (acc[mt][nt][r] - mean) * rstd * gn[col] + bn[col];
                    out[(size_t)n * 128 + col] = o;
                }
            }
        }
}

extern "C" void kernel_launch(void* const* d_in, const int* in_sizes, int n_in,
                              void* d_out, int out_size, void* d_ws, size_t ws_size,
                              hipStream_t stream) {
    const float* x          = (const float*)d_in[0];
    const float* edge_attr  = (const float*)d_in[1];
    const float* lg_x       = (const float*)d_in[2];
    const float* lg_ea      = (const float*)d_in[3];
    const float* W_line     = (const float*)d_in[4];
    const float* b_line     = (const float*)d_in[5];
    const float* W_gate     = (const float*)d_in[6];
    const float* b_gate     = (const float*)d_in[7];
    const float* W_atom     = (const float*)d_in[8];
    const float* b_atom     = (const float*)d_in[9];
    const float* g_node     = (const float*)d_in[10];
    const float* beta_node  = (const float*)d_in[11];
    const float* g_edge     = (const float*)d_in[12];
    const float* beta_edge  = (const float*)d_in[13];
    const int*   edge_index    = (const int*)d_in[14];
    const int*   lg_edge_index = (const int*)d_in[15];

    const int Nn  = in_sizes[0] / 128;
    const int En  = in_sizes[1] / 128;
    const int LEn = in_sizes[3];

    float* out_x    = (float*)d_out;
    float* out_edge = out_x + (size_t)Nn * 128;
    float* out_lg   = out_edge + (size_t)En * 128;

    short* wp_line = (short*)d_ws;            // 64 KB
    short* wp_gate = wp_line + 32768;         // 32 KB
    short* wp_atom = wp_gate + 16384;         // 64 KB
    float* cnt     = (float*)(wp_atom + 32768);

    const int* lg_src = lg_edge_index;
    const int* lg_dst = lg_edge_index + LEn;
    const int* col    = edge_index + En;

    hipMemsetAsync(out_x,  0, (size_t)Nn * 128 * sizeof(float), stream);
    hipMemsetAsync(out_lg, 0, (size_t)En * 128 * sizeof(float), stream);
    hipMemsetAsync(cnt,    0, (size_t)En * sizeof(float), stream);

    k_pack<<<16, 256, 0, stream>>>(W_line, wp_line, 4096);
    k_pack<<<8,  256, 0, stream>>>(W_gate, wp_gate, 2048);
    k_pack<<<16, 256, 0, stream>>>(W_atom, wp_atom, 4096);
    k_count<<<(LEn + 255) / 256, 256, 0, stream>>>(lg_dst, cnt, LEn);

    k_line_mfma<<<(LEn + 127) / 128, 256, 0, stream>>>(
        lg_x, lg_ea, wp_line, W_line, b_line, lg_src, lg_dst, out_lg, LEn);
    k_edge_fused<<<(En + 127) / 128, 256, 0, stream>>>(
        lg_x, edge_attr, cnt, g_edge, beta_edge, wp_gate, b_gate, col,
        out_lg, out_edge, out_x, En);
    k_atom_mfma<<<(Nn + 127) / 128, 256, 0, stream>>>(
        x, out_x, wp_atom, b_atom, g_node, beta_node, out_x, Nn);
}

// Round 4
// 2241.520 us; speedup vs baseline: 1.3043x; 1.3043x over previous
//
#include <hip/hip_runtime.h>

// ---------------------------------------------------------------------------
// EdgeGatedConv — bf16 MFMA. Round 4: fusion reverted (r3 post-mortem: fused
// kernel was latency-bound at 11.8% occupancy), k_line gathers a bf16 copy of
// lg_x (half the random-gather bytes; identical rounding to the old pack8).
//   prep: pack W_*, cvt lg_x->bf16 (ws permitting), cnt[dst]++
//   K1 k_line_mfma: msg = silu([lg_x[s],lg_x[d],lg_ea]@W_line+b) -> atomic out_lg[d]
//   K2 k_lg_final:  out_lg = lg_x + acc/max(cnt,1); out_edge = LN(edge_attr+out_lg)
//   K3 k_gate_mfma: gate=sigmoid(out_edge@W_gate+b); atomic gate*out_edge -> out_x[col]
//   K4 k_atom_mfma: h=silu([x,agg]@W_atom+b); out_x = LN(x+h)
//
// MFMA 16x16x32 bf16: A row = lane&15, B col = lane&15, k-slice = (lane>>4)*8+j
// on BOTH operands (consistent bijection). C/D: col = lane&15, row=(lane>>4)*4+reg.
// ---------------------------------------------------------------------------

typedef __attribute__((ext_vector_type(8))) short s16x8;
typedef __attribute__((ext_vector_type(4))) float f32x4;

__device__ __forceinline__ short f2bf(float f) {
    unsigned u = __float_as_uint(f);
    u += 0x7FFF + ((u >> 16) & 1);           // round-to-nearest-even
    return (short)(u >> 16);
}

__device__ __forceinline__ s16x8 pack8(const float* v) {
    s16x8 r;
    #pragma unroll
    for (int j = 0; j < 8; ++j) r[j] = f2bf(v[j]);
    return r;
}

// pack W[K][128] -> chunks: chunk c = g*128+col (g = k/8) holds W[g*8+j][col], j=0..7
__global__ __launch_bounds__(256) void k_pack(const float* __restrict__ W,
                                              short* __restrict__ P, int nchunk) {
    int c = blockIdx.x * 256 + threadIdx.x;
    if (c >= nchunk) return;
    int g = c >> 7, col = c & 127, k0 = g * 8;
    s16x8 v;
    #pragma unroll
    for (int j = 0; j < 8; ++j) v[j] = f2bf(W[(size_t)(k0 + j) * 128 + col]);
    ((s16x8*)P)[c] = v;
}

__global__ __launch_bounds__(256) void k_count(const int* __restrict__ dst,
                                               float* __restrict__ cnt, int n) {
    int i = blockIdx.x * 256 + threadIdx.x;
    if (i < n) atomicAdd(&cnt[dst[i]], 1.f);
}

// lg_x (f32) -> bf16 copy, 8 elems/thread/iter
__global__ __launch_bounds__(256) void k_cvt(const float* __restrict__ x,
                                             short* __restrict__ y, long n8) {
    long i = (long)blockIdx.x * 256 + threadIdx.x;
    const long stride = (long)gridDim.x * 256;
    for (; i < n8; i += stride) {
        float buf[8];
        *(float4*)&buf[0] = ((const float4*)x)[2 * i];
        *(float4*)&buf[4] = ((const float4*)x)[2 * i + 1];
        ((s16x8*)y)[i] = pack8(buf);
    }
}

// ---------------- K1: line-graph message GEMM + scatter (no LDS) ----------------
template <bool BF>
__global__ __launch_bounds__(256) void k_line_mfma(
    const float* __restrict__ lg_x, const short* __restrict__ lgx_bf,
    const float* __restrict__ lg_ea,
    const short* __restrict__ Wp, const float* __restrict__ W_line,
    const float* __restrict__ b_line,
    const int* __restrict__ lg_src, const int* __restrict__ lg_dst,
    float* __restrict__ lgacc, int LEn)
{
    const int tid = threadIdx.x;
    const int ln = tid & 63, wv = tid >> 6;
    const int l15 = ln & 15, lhi = ln >> 4;
    const int eb = blockIdx.x * 128 + wv * 32;
    const s16x8* Bv = (const s16x8*)Wp;

    const float *spf[2], *dpf[2];
    const short *spb[2], *dpb[2];
    #pragma unroll
    for (int mt = 0; mt < 2; ++mt) {
        int e = eb + mt * 16 + l15;
        int ec = e < LEn ? e : LEn - 1;
        if (BF) {
            spb[mt] = lgx_bf + (size_t)lg_src[ec] * 128;
            dpb[mt] = lgx_bf + (size_t)lg_dst[ec] * 128;
        } else {
            spf[mt] = lg_x + (size_t)lg_src[ec] * 128;
            dpf[mt] = lg_x + (size_t)lg_dst[ec] * 128;
        }
    }

    f32x4 acc[2][8];
    #pragma unroll
    for (int m = 0; m < 2; ++m)
        #pragma unroll
        for (int n = 0; n < 8; ++n) acc[m][n] = (f32x4){0.f, 0.f, 0.f, 0.f};

    #pragma unroll 2
    for (int kt = 0; kt < 8; ++kt) {
        int ko = (kt & 3) * 32 + lhi * 8;
        s16x8 a[2];
        #pragma unroll
        for (int mt = 0; mt < 2; ++mt) {
            if (BF) {
                const short* p = ((kt < 4) ? spb[mt] : dpb[mt]) + ko;
                a[mt] = *(const s16x8*)p;
            } else {
                const float* p = ((kt < 4) ? spf[mt] : dpf[mt]) + ko;
                float buf[8];
                *(float4*)&buf[0] = *(const float4*)p;
                *(float4*)&buf[4] = *(const float4*)(p + 4);
                a[mt] = pack8(buf);
            }
        }
        const s16x8* brow = Bv + (size_t)(kt * 4 + lhi) * 128 + l15;
        #pragma unroll
        for (int nt = 0; nt < 8; ++nt) {
            s16x8 b = brow[nt * 16];
            acc[0][nt] = __builtin_amdgcn_mfma_f32_16x16x32_bf16(a[0], b, acc[0][nt], 0, 0, 0);
            acc[1][nt] = __builtin_amdgcn_mfma_f32_16x16x32_bf16(a[1], b, acc[1][nt], 0, 0, 0);
        }
    }

    // hoist per-(mt,r) scalars out of the nt loop (was 64 redundant loads)
    float eav[2][4];
    int dstv[2][4];
    #pragma unroll
    for (int mt = 0; mt < 2; ++mt)
        #pragma unroll
        for (int r = 0; r < 4; ++r) {
            int e = eb + mt * 16 + lhi * 4 + r;
            int ec = e < LEn ? e : 0;
            eav[mt][r]  = lg_ea[ec];
            dstv[mt][r] = lg_dst[ec];
        }

    #pragma unroll
    for (int nt = 0; nt < 8; ++nt) {
        int col = nt * 16 + l15;
        float wl = W_line[(size_t)256 * 128 + col];
        float bs = b_line[col];
        #pragma unroll
        for (int mt = 0; mt < 2; ++mt)
            #pragma unroll
            for (int r = 0; r < 4; ++r) {
                int e = eb + mt * 16 + lhi * 4 + r;
                if (e < LEn) {
                    float v = acc[mt][nt][r] + bs + wl * eav[mt][r];
                    float s = v / (1.f + __expf(-v));
                    atomicAdd(&lgacc[(size_t)dstv[mt][r] * 128 + col], s);
                }
            }
    }
}

// ---------------- K2: lg finalize + edge LayerNorm (round-2 version) ----------------
__global__ __launch_bounds__(256) void k_lg_final_edge_ln(
    const float* __restrict__ lg_x, const float* __restrict__ edge_attr,
    const float* __restrict__ cnt,
    const float* __restrict__ g_edge, const float* __restrict__ beta_edge,
    float* __restrict__ out_lg, float* __restrict__ out_edge, int En)
{
    const int wave = threadIdx.x >> 6;
    const int lane = threadIdx.x & 63;
    const int e = blockIdx.x * 4 + wave;
    if (e >= En) return;
    const size_t base = (size_t)e * 128 + lane * 2;
    float2 accv = *(const float2*)&out_lg[base];
    float2 lgv  = *(const float2*)&lg_x[base];
    float inv = 1.f / fmaxf(cnt[e], 1.f);
    float2 lnew = make_float2(fmaf(accv.x, inv, lgv.x), fmaf(accv.y, inv, lgv.y));
    *(float2*)&out_lg[base] = lnew;
    float2 ea = *(const float2*)&edge_attr[base];
    float t0 = ea.x + lnew.x, t1 = ea.y + lnew.y;
    float s = t0 + t1, sq = t0 * t0 + t1 * t1;
    #pragma unroll
    for (int off = 32; off; off >>= 1) {
        s  += __shfl_xor(s, off);
        sq += __shfl_xor(sq, off);
    }
    float mean = s * (1.f / 128.f);
    float var  = sq * (1.f / 128.f) - mean * mean;
    float r = rsqrtf(var + 1e-5f);
    int j0 = lane * 2;
    float o0 = (t0 - mean) * r * g_edge[j0]     + beta_edge[j0];
    float o1 = (t1 - mean) * r * g_edge[j0 + 1] + beta_edge[j0 + 1];
    *(float2*)&out_edge[base] = make_float2(o0, o1);
}

// ---------------- K3: gate GEMM + gated scatter (round-2 LDS version) ----------------
__global__ __launch_bounds__(256) void k_gate_mfma(
    const float* __restrict__ Ein, const short* __restrict__ Wp,
    const float* __restrict__ bg, const int* __restrict__ colidx,
    float* __restrict__ agg, int En)
{
    __shared__ s16x8 B[2048];                 // 32 KB
    const int tid = threadIdx.x;
    #pragma unroll
    for (int i = 0; i < 8; ++i)
        ((float4*)B)[tid + i * 256] = ((const float4*)Wp)[tid + i * 256];
    __syncthreads();

    const int ln = tid & 63, wv = tid >> 6;
    const int l15 = ln & 15, lhi = ln >> 4;
    const int eb = blockIdx.x * 128 + wv * 32;

    const float* rp[2];
    #pragma unroll
    for (int mt = 0; mt < 2; ++mt) {
        int e = eb + mt * 16 + l15;
        rp[mt] = Ein + (size_t)(e < En ? e : En - 1) * 128;
    }

    f32x4 acc[2][8];
    #pragma unroll
    for (int m = 0; m < 2; ++m)
        #pragma unroll
        for (int n = 0; n < 8; ++n) acc[m][n] = (f32x4){0.f, 0.f, 0.f, 0.f};

    #pragma unroll 2
    for (int kt = 0; kt < 4; ++kt) {
        int ko = kt * 32 + lhi * 8;
        s16x8 a[2];
        #pragma unroll
        for (int mt = 0; mt < 2; ++mt) {
            float buf[8];
            *(float4*)&buf[0] = *(const float4*)(rp[mt] + ko);
            *(float4*)&buf[4] = *(const float4*)(rp[mt] + ko + 4);
            a[mt] = pack8(buf);
        }
        const s16x8* brow = &B[(kt * 4 + lhi) * 128 + l15];
        #pragma unroll
        for (int nt = 0; nt < 8; ++nt) {
            s16x8 b = brow[nt * 16];
            acc[0][nt] = __builtin_amdgcn_mfma_f32_16x16x32_bf16(a[0], b, acc[0][nt], 0, 0, 0);
            acc[1][nt] = __builtin_amdgcn_mfma_f32_16x16x32_bf16(a[1], b, acc[1][nt], 0, 0, 0);
        }
    }

    int colv[2][4];
    #pragma unroll
    for (int mt = 0; mt < 2; ++mt)
        #pragma unroll
        for (int r = 0; r < 4; ++r) {
            int e = eb + mt * 16 + lhi * 4 + r;
            colv[mt][r] = colidx[e < En ? e : 0];
        }

    #pragma unroll
    for (int nt = 0; nt < 8; ++nt) {
        int col = nt * 16 + l15;
        float bs = bg[col];
        #pragma unroll
        for (int mt = 0; mt < 2; ++mt)
            #pragma unroll
            for (int r = 0; r < 4; ++r) {
                int e = eb + mt * 16 + lhi * 4 + r;
                if (e < En) {
                    float g = 1.f / (1.f + __expf(-(acc[mt][nt][r] + bs)));
                    float val = g * Ein[(size_t)e * 128 + col];
                    atomicAdd(&agg[(size_t)colv[mt][r] * 128 + col], val);
                }
            }
    }
}

// ---------------- K4: atom GEMM + residual + in-register LayerNorm (no LDS) ----------------
__global__ __launch_bounds__(256) void k_atom_mfma(
    const float* __restrict__ x, const float* __restrict__ aggin,
    const short* __restrict__ Wp, const float* __restrict__ ba,
    const float* __restrict__ gn, const float* __restrict__ bn,
    float* __restrict__ out, int Nn)
{
    const int tid = threadIdx.x;
    const int ln = tid & 63, wv = tid >> 6;
    const int l15 = ln & 15, lhi = ln >> 4;
    const int nb = blockIdx.x * 128 + wv * 32;
    const s16x8* Bv = (const s16x8*)Wp;

    const float *xp[2], *ap[2];
    #pragma unroll
    for (int mt = 0; mt < 2; ++mt) {
        int n = nb + mt * 16 + l15;
        size_t nc = (size_t)(n < Nn ? n : Nn - 1) * 128;
        xp[mt] = x + nc;
        ap[mt] = aggin + nc;
    }

    f32x4 acc[2][8];
    #pragma unroll
    for (int m = 0; m < 2; ++m)
        #pragma unroll
        for (int n = 0; n < 8; ++n) acc[m][n] = (f32x4){0.f, 0.f, 0.f, 0.f};

    #pragma unroll 2
    for (int kt = 0; kt < 8; ++kt) {
        int ko = (kt & 3) * 32 + lhi * 8;
        s16x8 a[2];
        #pragma unroll
        for (int mt = 0; mt < 2; ++mt) {
            const float* p = ((kt < 4) ? xp[mt] : ap[mt]) + ko;
            float buf[8];
            *(float4*)&buf[0] = *(const float4*)p;
            *(float4*)&buf[4] = *(const float4*)(p + 4);
            a[mt] = pack8(buf);
        }
        const s16x8* brow = Bv + (size_t)(kt * 4 + lhi) * 128 + l15;
        #pragma unroll
        for (int nt = 0; nt < 8; ++nt) {
            s16x8 b = brow[nt * 16];
            acc[0][nt] = __builtin_amdgcn_mfma_f32_16x16x32_bf16(a[0], b, acc[0][nt], 0, 0, 0);
            acc[1][nt] = __builtin_amdgcn_mfma_f32_16x16x32_bf16(a[1], b, acc[1][nt], 0, 0, 0);
        }
    }

    #pragma unroll
    for (int mt = 0; mt < 2; ++mt)
        #pragma unroll
        for (int r = 0; r < 4; ++r) {
            int n = nb + mt * 16 + lhi * 4 + r;
            size_t nr = (size_t)(n < Nn ? n : 0) * 128;
            float s = 0.f, sq = 0.f;
            #pragma unroll
            for (int nt = 0; nt < 8; ++nt) {
                int col = nt * 16 + l15;
                float v = acc[mt][nt][r] + ba[col];
                float h = v / (1.f + __expf(-v));
                float t = x[nr + col] + h;
                acc[mt][nt][r] = t;
                s += t; sq += t * t;
            }
            #pragma unroll
            for (int off = 8; off; off >>= 1) {
                s  += __shfl_xor(s, off);
                sq += __shfl_xor(sq, off);
            }
            float mean = s * (1.f / 128.f);
            float var  = sq * (1.f / 128.f) - mean * mean;
            float rstd = rsqrtf(var + 1e-5f);
            if (n < Nn) {
                #pragma unroll
                for (int nt = 0; nt < 8; ++nt) {
                    int col = nt * 16 + l15;
                    float o = (acc[mt][nt][r] - mean) * rstd * gn[col] + bn[col];
                    out[(size_t)n * 128 + col] = o;
                }
            }
        }
}

extern "C" void kernel_launch(void* const* d_in, const int* in_sizes, int n_in,
                              void* d_out, int out_size, void* d_ws, size_t ws_size,
                              hipStream_t stream) {
    const float* x          = (const float*)d_in[0];
    const float* edge_attr  = (const float*)d_in[1];
    const float* lg_x       = (const float*)d_in[2];
    const float* lg_ea      = (const float*)d_in[3];
    const float* W_line     = (const float*)d_in[4];
    const float* b_line     = (const float*)d_in[5];
    const float* W_gate     = (const float*)d_in[6];
    const float* b_gate     = (const float*)d_in[7];
    const float* W_atom     = (const float*)d_in[8];
    const float* b_atom     = (const float*)d_in[9];
    const float* g_node     = (const float*)d_in[10];
    const float* beta_node  = (const float*)d_in[11];
    const float* g_edge     = (const float*)d_in[12];
    const float* beta_edge  = (const float*)d_in[13];
    const int*   edge_index    = (const int*)d_in[14];
    const int*   lg_edge_index = (const int*)d_in[15];

    const int Nn  = in_sizes[0] / 128;
    const int En  = in_sizes[1] / 128;
    const int LEn = in_sizes[3];

    float* out_x    = (float*)d_out;
    float* out_edge = out_x + (size_t)Nn * 128;
    float* out_lg   = out_edge + (size_t)En * 128;

    short* wp_line = (short*)d_ws;            // 64 KB
    short* wp_gate = wp_line + 32768;         // 32 KB
    short* wp_atom = wp_gate + 16384;         // 64 KB
    float* cnt     = (float*)(wp_atom + 32768);
    short* lgx_bf  = (short*)(cnt + En);      // 256 MB if available

    const size_t need_bf = (size_t)(81920 * 2) + (size_t)En * 4 + (size_t)En * 128 * 2;
    const bool use_bf = ws_size >= need_bf;

    const int* lg_src = lg_edge_index;
    const int* lg_dst = lg_edge_index + LEn;
    const int* col    = edge_index + En;

    hipMemsetAsync(out_x,  0, (size_t)Nn * 128 * sizeof(float), stream);
    hipMemsetAsync(out_lg, 0, (size_t)En * 128 * sizeof(float), stream);
    hipMemsetAsync(cnt,    0, (size_t)En * sizeof(float), stream);

    k_pack<<<16, 256, 0, stream>>>(W_line, wp_line, 4096);
    k_pack<<<8,  256, 0, stream>>>(W_gate, wp_gate, 2048);
    k_pack<<<16, 256, 0, stream>>>(W_atom, wp_atom, 4096);
    k_count<<<(LEn + 255) / 256, 256, 0, stream>>>(lg_dst, cnt, LEn);
    if (use_bf)
        k_cvt<<<2048, 256, 0, stream>>>(lg_x, lgx_bf, (long)En * 16);

    if (use_bf)
        k_line_mfma<true><<<(LEn + 127) / 128, 256, 0, stream>>>(
            lg_x, lgx_bf, lg_ea, wp_line, W_line, b_line, lg_src, lg_dst, out_lg, LEn);
    else
        k_line_mfma<false><<<(LEn + 127) / 128, 256, 0, stream>>>(
            lg_x, lgx_bf, lg_ea, wp_line, W_line, b_line, lg_src, lg_dst, out_lg, LEn);

    k_lg_final_edge_ln<<<(En + 3) / 4, 256, 0, stream>>>(
        lg_x, edge_attr, cnt, g_edge, beta_edge, out_lg, out_edge, En);
    k_gate_mfma<<<(En + 127) / 128, 256, 0, stream>>>(
        out_edge, wp_gate, b_gate, col, out_x, En);
    k_atom_mfma<<<(Nn + 127) / 128, 256, 0, stream>>>(
        x, out_x, wp_atom, b_atom, g_node, beta_node, out_x, Nn);
}

// Round 5
// 1856.848 us; speedup vs baseline: 1.5745x; 1.2072x over previous
//
#include <hip/hip_runtime.h>

// ---------------------------------------------------------------------------
// EdgeGatedConv — bf16 MFMA + CSR-gather scatters (round 5).
// r4 post-mortem: both scatter kernels were atomic-latency-bound (128M scalar
// atomics each). This round removes ALL heavy atomics via device-built CSRs:
//   CSR build: hist -> block scan -> bsum scan -> add -> perm fill   (x2)
//   K1 k_line_csr:  GEMM -> msg bf16 rows (stored in out_edge region, LDS repack)
//   K2a k_lg_gather: out_lg = lg_x + mean(msg[perm])        (wave/lg-node)
//   K2b k_edge_ln:   out_edge = LN(edge_attr + out_lg)
//   K3 k_gate_csr:  GEMM -> gated = sigmoid(.)*enew bf16 -> ws
//   K3b k_atom_gather: out_x = sum(gated[perm])             (wave/node)
//   K4 k_atom_mfma: h=silu([x,agg]@W_atom+b); out_x = LN(x+h)
// Fallback to the r4 atomic pipeline if ws_size < ~279 MB.
// MFMA 16x16x32 bf16: A row=lane&15, B col=lane&15, k-slice=(lane>>4)*8+j on
// both operands. C/D: col=lane&15, row=(lane>>4)*4+reg.
// ---------------------------------------------------------------------------

typedef __attribute__((ext_vector_type(8))) short s16x8;
typedef __attribute__((ext_vector_type(4))) float f32x4;

#define SCAN_CHUNK 2048

__device__ __forceinline__ short f2bf(float f) {
    unsigned u = __float_as_uint(f);
    u += 0x7FFF + ((u >> 16) & 1);
    return (short)(u >> 16);
}
__device__ __forceinline__ float bf2f(unsigned short h) {
    return __uint_as_float(((unsigned)h) << 16);
}
__device__ __forceinline__ s16x8 pack8(const float* v) {
    s16x8 r;
    #pragma unroll
    for (int j = 0; j < 8; ++j) r[j] = f2bf(v[j]);
    return r;
}

// ---------------- prep ----------------
__global__ __launch_bounds__(256) void k_pack(const float* __restrict__ W,
                                              short* __restrict__ P, int nchunk) {
    int c = blockIdx.x * 256 + threadIdx.x;
    if (c >= nchunk) return;
    int g = c >> 7, col = c & 127, k0 = g * 8;
    s16x8 v;
    #pragma unroll
    for (int j = 0; j < 8; ++j) v[j] = f2bf(W[(size_t)(k0 + j) * 128 + col]);
    ((s16x8*)P)[c] = v;
}

__global__ __launch_bounds__(256) void k_cvt(const float* __restrict__ x,
                                             short* __restrict__ y, long n8) {
    long i = (long)blockIdx.x * 256 + threadIdx.x;
    const long stride = (long)gridDim.x * 256;
    for (; i < n8; i += stride) {
        float buf[8];
        *(float4*)&buf[0] = ((const float4*)x)[2 * i];
        *(float4*)&buf[4] = ((const float4*)x)[2 * i + 1];
        ((s16x8*)y)[i] = pack8(buf);
    }
}

// ---------------- CSR build ----------------
__global__ __launch_bounds__(256) void k_hist(const int* __restrict__ idx,
                                              int* __restrict__ deg, int n) {
    int i = blockIdx.x * 256 + threadIdx.x;
    if (i < n) atomicAdd(&deg[idx[i]], 1);
}

__global__ __launch_bounds__(256) void k_scan_block(const int* __restrict__ in, int n,
                                                    int* __restrict__ out,
                                                    int* __restrict__ bsum) {
    __shared__ int ts[256];
    const int b = blockIdx.x, t = threadIdx.x;
    const int base = b * SCAN_CHUNK + t * 8;
    int v[8]; int s = 0;
    #pragma unroll
    for (int i = 0; i < 8; ++i) { v[i] = (base + i < n) ? in[base + i] : 0; s += v[i]; }
    ts[t] = s;
    __syncthreads();
    int x = s;
    for (int off = 1; off < 256; off <<= 1) {
        int y = (t >= off) ? ts[t - off] : 0;
        __syncthreads();
        x += y; ts[t] = x;
        __syncthreads();
    }
    if (t == 255) bsum[b] = x;
    int run = x - s;
    #pragma unroll
    for (int i = 0; i < 8; ++i) {
        if (base + i < n) out[base + i] = run;
        run += v[i];
    }
}

__global__ void k_scan_bsum(int* __restrict__ bsum, int nb) {   // 1 wave
    const int lane = threadIdx.x;
    int carry = 0;
    for (int base = 0; base < nb; base += 64) {
        int i = base + lane;
        int v = (i < nb) ? bsum[i] : 0;
        int inc = v;
        #pragma unroll
        for (int off = 1; off < 64; off <<= 1) {
            int t = __shfl_up(inc, off);
            if (lane >= off) inc += t;
        }
        if (i < nb) bsum[i] = inc - v + carry;
        carry += __shfl(inc, 63);
    }
}

__global__ __launch_bounds__(256) void k_scan_add(int* __restrict__ off,
                                                  const int* __restrict__ bsum,
                                                  int n, int nedge) {
    int i = blockIdx.x * 256 + threadIdx.x;
    if (i < n) off[i] += bsum[i / SCAN_CHUNK];
    if (i == 0) off[n] = nedge;
}

__global__ __launch_bounds__(256) void k_fill(const int* __restrict__ idx,
                                              const int* __restrict__ off,
                                              int* __restrict__ cur,
                                              int* __restrict__ perm, int n) {
    int i = blockIdx.x * 256 + threadIdx.x;
    if (i < n) {
        int s = idx[i];
        int p = atomicAdd(&cur[s], 1);
        perm[off[s] + p] = i;
    }
}

// ---------------- K1: line GEMM -> msg bf16 (CSR tier) ----------------
__global__ __launch_bounds__(256) void k_line_csr(
    const short* __restrict__ lgx_bf, const float* __restrict__ lg_ea,
    const short* __restrict__ Wp, const float* __restrict__ W_line,
    const float* __restrict__ b_line,
    const int* __restrict__ lg_src, const int* __restrict__ lg_dst,
    short* __restrict__ msg, int LEn)
{
    __shared__ __align__(16) short sh[128][136];
    const int tid = threadIdx.x;
    const int ln = tid & 63, wv = tid >> 6;
    const int l15 = ln & 15, lhi = ln >> 4;
    const int eb = blockIdx.x * 128 + wv * 32;
    const s16x8* Bv = (const s16x8*)Wp;

    const short *sp[2], *dp[2];
    #pragma unroll
    for (int mt = 0; mt < 2; ++mt) {
        int e = eb + mt * 16 + l15;
        int ec = e < LEn ? e : LEn - 1;
        sp[mt] = lgx_bf + (size_t)lg_src[ec] * 128;
        dp[mt] = lgx_bf + (size_t)lg_dst[ec] * 128;
    }

    f32x4 acc[2][8];
    #pragma unroll
    for (int m = 0; m < 2; ++m)
        #pragma unroll
        for (int n = 0; n < 8; ++n) acc[m][n] = (f32x4){0.f, 0.f, 0.f, 0.f};

    #pragma unroll 2
    for (int kt = 0; kt < 8; ++kt) {
        int ko = (kt & 3) * 32 + lhi * 8;
        s16x8 a[2];
        #pragma unroll
        for (int mt = 0; mt < 2; ++mt)
            a[mt] = *(const s16x8*)(((kt < 4) ? sp[mt] : dp[mt]) + ko);
        const s16x8* brow = Bv + (size_t)(kt * 4 + lhi) * 128 + l15;
        #pragma unroll
        for (int nt = 0; nt < 8; ++nt) {
            s16x8 b = brow[nt * 16];
            acc[0][nt] = __builtin_amdgcn_mfma_f32_16x16x32_bf16(a[0], b, acc[0][nt], 0, 0, 0);
            acc[1][nt] = __builtin_amdgcn_mfma_f32_16x16x32_bf16(a[1], b, acc[1][nt], 0, 0, 0);
        }
    }

    float eav[2][4];
    #pragma unroll
    for (int mt = 0; mt < 2; ++mt)
        #pragma unroll
        for (int r = 0; r < 4; ++r) {
            int e = eb + mt * 16 + lhi * 4 + r;
            eav[mt][r] = lg_ea[e < LEn ? e : 0];
        }

    #pragma unroll
    for (int nt = 0; nt < 8; ++nt) {
        int col = nt * 16 + l15;
        float wl = W_line[(size_t)256 * 128 + col];
        float bs = b_line[col];
        #pragma unroll
        for (int mt = 0; mt < 2; ++mt)
            #pragma unroll
            for (int r = 0; r < 4; ++r) {
                float v = acc[mt][nt][r] + bs + wl * eav[mt][r];
                float s = v / (1.f + __expf(-v));
                sh[wv * 32 + mt * 16 + lhi * 4 + r][col] = f2bf(s);
            }
    }
    __syncthreads();
    #pragma unroll
    for (int i = 0; i < 8; ++i) {
        int c = tid + i * 256;                 // 128 rows x 16 chunks
        int row = c >> 4, q = c & 15;
        int e = blockIdx.x * 128 + row;
        if (e < LEn)
            *(s16x8*)&msg[(size_t)e * 128 + q * 8] = *(const s16x8*)&sh[row][q * 8];
    }
}

// ---------------- K2a: gather-mean + residual ----------------
__global__ __launch_bounds__(256) void k_lg_gather(
    const short* __restrict__ msg, const float* __restrict__ lg_x,
    const int* __restrict__ off, const int* __restrict__ perm,
    float* __restrict__ out_lg, int En)
{
    const int wave = threadIdx.x >> 6, lane = threadIdx.x & 63;
    const int e = blockIdx.x * 4 + wave;
    if (e >= En) return;
    const int o0 = off[e], o1 = off[e + 1];
    float s0 = 0.f, s1 = 0.f;
    for (int j = o0; j < o1; ++j) {
        int m = perm[j];
        ushort2 u = *(const ushort2*)&msg[(size_t)m * 128 + lane * 2];
        s0 += bf2f(u.x); s1 += bf2f(u.y);
    }
    const float inv = 1.f / fmaxf((float)(o1 - o0), 1.f);
    const size_t base = (size_t)e * 128 + lane * 2;
    float2 lx = *(const float2*)&lg_x[base];
    *(float2*)&out_lg[base] = make_float2(fmaf(s0, inv, lx.x), fmaf(s1, inv, lx.y));
}

// ---------------- K2b: edge LayerNorm ----------------
__global__ __launch_bounds__(256) void k_edge_ln(
    const float* __restrict__ lnew, const float* __restrict__ edge_attr,
    const float* __restrict__ g_edge, const float* __restrict__ beta_edge,
    float* __restrict__ out_edge, int En)
{
    const int wave = threadIdx.x >> 6, lane = threadIdx.x & 63;
    const int e = blockIdx.x * 4 + wave;
    if (e >= En) return;
    const size_t base = (size_t)e * 128 + lane * 2;
    float2 lv = *(const float2*)&lnew[base];
    float2 ea = *(const float2*)&edge_attr[base];
    float t0 = ea.x + lv.x, t1 = ea.y + lv.y;
    float s = t0 + t1, sq = t0 * t0 + t1 * t1;
    #pragma unroll
    for (int off = 32; off; off >>= 1) {
        s  += __shfl_xor(s, off);
        sq += __shfl_xor(sq, off);
    }
    float mean = s * (1.f / 128.f);
    float var  = sq * (1.f / 128.f) - mean * mean;
    float r = rsqrtf(var + 1e-5f);
    int j0 = lane * 2;
    float o0 = (t0 - mean) * r * g_edge[j0]     + beta_edge[j0];
    float o1 = (t1 - mean) * r * g_edge[j0 + 1] + beta_edge[j0 + 1];
    *(float2*)&out_edge[base] = make_float2(o0, o1);
}

// ---------------- K3: gate GEMM -> gated bf16 (CSR tier) ----------------
__global__ __launch_bounds__(256) void k_gate_csr(
    const float* __restrict__ Ein, const short* __restrict__ Wp,
    const float* __restrict__ bg, short* __restrict__ gated, int En)
{
    __shared__ __align__(16) short sh[128][136];
    const int tid = threadIdx.x;
    const int ln = tid & 63, wv = tid >> 6;
    const int l15 = ln & 15, lhi = ln >> 4;
    const int eb = blockIdx.x * 128 + wv * 32;
    const s16x8* Bv = (const s16x8*)Wp;

    const float* rp[2];
    #pragma unroll
    for (int mt = 0; mt < 2; ++mt) {
        int e = eb + mt * 16 + l15;
        rp[mt] = Ein + (size_t)(e < En ? e : En - 1) * 128;
    }

    f32x4 acc[2][8];
    #pragma unroll
    for (int m = 0; m < 2; ++m)
        #pragma unroll
        for (int n = 0; n < 8; ++n) acc[m][n] = (f32x4){0.f, 0.f, 0.f, 0.f};

    #pragma unroll 2
    for (int kt = 0; kt < 4; ++kt) {
        int ko = kt * 32 + lhi * 8;
        s16x8 a[2];
        #pragma unroll
        for (int mt = 0; mt < 2; ++mt) {
            float buf[8];
            *(float4*)&buf[0] = *(const float4*)(rp[mt] + ko);
            *(float4*)&buf[4] = *(const float4*)(rp[mt] + ko + 4);
            a[mt] = pack8(buf);
        }
        const s16x8* brow = Bv + (size_t)(kt * 4 + lhi) * 128 + l15;
        #pragma unroll
        for (int nt = 0; nt < 8; ++nt) {
            s16x8 b = brow[nt * 16];
            acc[0][nt] = __builtin_amdgcn_mfma_f32_16x16x32_bf16(a[0], b, acc[0][nt], 0, 0, 0);
            acc[1][nt] = __builtin_amdgcn_mfma_f32_16x16x32_bf16(a[1], b, acc[1][nt], 0, 0, 0);
        }
    }

    #pragma unroll
    for (int nt = 0; nt < 8; ++nt) {
        int col = nt * 16 + l15;
        float bs = bg[col];
        #pragma unroll
        for (int mt = 0; mt < 2; ++mt)
            #pragma unroll
            for (int r = 0; r < 4; ++r) {
                int e = eb + mt * 16 + lhi * 4 + r;
                int ec = e < En ? e : En - 1;
                float g = 1.f / (1.f + __expf(-(acc[mt][nt][r] + bs)));
                float val = g * Ein[(size_t)ec * 128 + col];
                sh[wv * 32 + mt * 16 + lhi * 4 + r][col] = f2bf(val);
            }
    }
    __syncthreads();
    #pragma unroll
    for (int i = 0; i < 8; ++i) {
        int c = tid + i * 256;
        int row = c >> 4, q = c & 15;
        int e = blockIdx.x * 128 + row;
        if (e < En)
            *(s16x8*)&gated[(size_t)e * 128 + q * 8] = *(const s16x8*)&sh[row][q * 8];
    }
}

// ---------------- K3b: atom aggregation gather ----------------
__global__ __launch_bounds__(256) void k_atom_gather(
    const short* __restrict__ gated,
    const int* __restrict__ off, const int* __restrict__ perm,
    float* __restrict__ agg, int Nn)
{
    const int wave = threadIdx.x >> 6, lane = threadIdx.x & 63;
    const int n = blockIdx.x * 4 + wave;
    if (n >= Nn) return;
    const int o0 = off[n], o1 = off[n + 1];
    float s0 = 0.f, s1 = 0.f;
    for (int j = o0; j < o1; ++j) {
        int e = perm[j];
        ushort2 u = *(const ushort2*)&gated[(size_t)e * 128 + lane * 2];
        s0 += bf2f(u.x); s1 += bf2f(u.y);
    }
    *(float2*)&agg[(size_t)n * 128 + lane * 2] = make_float2(s0, s1);
}

// ---------------- K4: atom GEMM + residual + in-register LN ----------------
__global__ __launch_bounds__(256) void k_atom_mfma(
    const float* __restrict__ x, const float* __restrict__ aggin,
    const short* __restrict__ Wp, const float* __restrict__ ba,
    const float* __restrict__ gn, const float* __restrict__ bn,
    float* __restrict__ out, int Nn)
{
    const int tid = threadIdx.x;
    const int ln = tid & 63, wv = tid >> 6;
    const int l15 = ln & 15, lhi = ln >> 4;
    const int nb = blockIdx.x * 128 + wv * 32;
    const s16x8* Bv = (const s16x8*)Wp;

    const float *xp[2], *ap[2];
    #pragma unroll
    for (int mt = 0; mt < 2; ++mt) {
        int n = nb + mt * 16 + l15;
        size_t nc = (size_t)(n < Nn ? n : Nn - 1) * 128;
        xp[mt] = x + nc;
        ap[mt] = aggin + nc;
    }

    f32x4 acc[2][8];
    #pragma unroll
    for (int m = 0; m < 2; ++m)
        #pragma unroll
        for (int n = 0; n < 8; ++n) acc[m][n] = (f32x4){0.f, 0.f, 0.f, 0.f};

    #pragma unroll 2
    for (int kt = 0; kt < 8; ++kt) {
        int ko = (kt & 3) * 32 + lhi * 8;
        s16x8 a[2];
        #pragma unroll
        for (int mt = 0; mt < 2; ++mt) {
            const float* p = ((kt < 4) ? xp[mt] : ap[mt]) + ko;
            float buf[8];
            *(float4*)&buf[0] = *(const float4*)p;
            *(float4*)&buf[4] = *(const float4*)(p + 4);
            a[mt] = pack8(buf);
        }
        const s16x8* brow = Bv + (size_t)(kt * 4 + lhi) * 128 + l15;
        #pragma unroll
        for (int nt = 0; nt < 8; ++nt) {
            s16x8 b = brow[nt * 16];
            acc[0][nt] = __builtin_amdgcn_mfma_f32_16x16x32_bf16(a[0], b, acc[0][nt], 0, 0, 0);
            acc[1][nt] = __builtin_amdgcn_mfma_f32_16x16x32_bf16(a[1], b, acc[1][nt], 0, 0, 0);
        }
    }

    #pragma unroll
    for (int mt = 0; mt < 2; ++mt)
        #pragma unroll
        for (int r = 0; r < 4; ++r) {
            int n = nb + mt * 16 + lhi * 4 + r;
            size_t nr = (size_t)(n < Nn ? n : 0) * 128;
            float s = 0.f, sq = 0.f;
            #pragma unroll
            for (int nt = 0; nt < 8; ++nt) {
                int col = nt * 16 + l15;
                float v = acc[mt][nt][r] + ba[col];
                float h = v / (1.f + __expf(-v));
                float t = x[nr + col] + h;
                acc[mt][nt][r] = t;
                s += t; sq += t * t;
            }
            #pragma unroll
            for (int off = 8; off; off >>= 1) {
                s  += __shfl_xor(s, off);
                sq += __shfl_xor(sq, off);
            }
            float mean = s * (1.f / 128.f);
            float var  = sq * (1.f / 128.f) - mean * mean;
            float rstd = rsqrtf(var + 1e-5f);
            if (n < Nn) {
                #pragma unroll
                for (int nt = 0; nt < 8; ++nt) {
                    int col = nt * 16 + l15;
                    float o = (acc[mt][nt][r] - mean) * rstd * gn[col] + bn[col];
                    out[(size_t)n * 128 + col] = o;
                }
            }
        }
}

// ================= fallback (r4) kernels =================
__global__ __launch_bounds__(256) void k_count(const int* __restrict__ dst,
                                               float* __restrict__ cnt, int n) {
    int i = blockIdx.x * 256 + threadIdx.x;
    if (i < n) atomicAdd(&cnt[dst[i]], 1.f);
}

template <bool BF>
__global__ __launch_bounds__(256) void k_line_atomic(
    const float* __restrict__ lg_x, const short* __restrict__ lgx_bf,
    const float* __restrict__ lg_ea,
    const short* __restrict__ Wp, const float* __restrict__ W_line,
    const float* __restrict__ b_line,
    const int* __restrict__ lg_src, const int* __restrict__ lg_dst,
    float* __restrict__ lgacc, int LEn)
{
    const int tid = threadIdx.x;
    const int ln = tid & 63, wv = tid >> 6;
    const int l15 = ln & 15, lhi = ln >> 4;
    const int eb = blockIdx.x * 128 + wv * 32;
    const s16x8* Bv = (const s16x8*)Wp;

    const float *spf[2], *dpf[2];
    const short *spb[2], *dpb[2];
    #pragma unroll
    for (int mt = 0; mt < 2; ++mt) {
        int e = eb + mt * 16 + l15;
        int ec = e < LEn ? e : LEn - 1;
        if (BF) { spb[mt] = lgx_bf + (size_t)lg_src[ec] * 128;
                  dpb[mt] = lgx_bf + (size_t)lg_dst[ec] * 128; }
        else    { spf[mt] = lg_x + (size_t)lg_src[ec] * 128;
                  dpf[mt] = lg_x + (size_t)lg_dst[ec] * 128; }
    }

    f32x4 acc[2][8];
    #pragma unroll
    for (int m = 0; m < 2; ++m)
        #pragma unroll
        for (int n = 0; n < 8; ++n) acc[m][n] = (f32x4){0.f, 0.f, 0.f, 0.f};

    #pragma unroll 2
    for (int kt = 0; kt < 8; ++kt) {
        int ko = (kt & 3) * 32 + lhi * 8;
        s16x8 a[2];
        #pragma unroll
        for (int mt = 0; mt < 2; ++mt) {
            if (BF) a[mt] = *(const s16x8*)(((kt < 4) ? spb[mt] : dpb[mt]) + ko);
            else {
                const float* p = ((kt < 4) ? spf[mt] : dpf[mt]) + ko;
                float buf[8];
                *(float4*)&buf[0] = *(const float4*)p;
                *(float4*)&buf[4] = *(const float4*)(p + 4);
                a[mt] = pack8(buf);
            }
        }
        const s16x8* brow = Bv + (size_t)(kt * 4 + lhi) * 128 + l15;
        #pragma unroll
        for (int nt = 0; nt < 8; ++nt) {
            s16x8 b = brow[nt * 16];
            acc[0][nt] = __builtin_amdgcn_mfma_f32_16x16x32_bf16(a[0], b, acc[0][nt], 0, 0, 0);
            acc[1][nt] = __builtin_amdgcn_mfma_f32_16x16x32_bf16(a[1], b, acc[1][nt], 0, 0, 0);
        }
    }

    float eav[2][4]; int dstv[2][4];
    #pragma unroll
    for (int mt = 0; mt < 2; ++mt)
        #pragma unroll
        for (int r = 0; r < 4; ++r) {
            int e = eb + mt * 16 + lhi * 4 + r;
            int ec = e < LEn ? e : 0;
            eav[mt][r] = lg_ea[ec];
            dstv[mt][r] = lg_dst[ec];
        }

    #pragma unroll
    for (int nt = 0; nt < 8; ++nt) {
        int col = nt * 16 + l15;
        float wl = W_line[(size_t)256 * 128 + col];
        float bs = b_line[col];
        #pragma unroll
        for (int mt = 0; mt < 2; ++mt)
            #pragma unroll
            for (int r = 0; r < 4; ++r) {
                int e = eb + mt * 16 + lhi * 4 + r;
                if (e < LEn) {
                    float v = acc[mt][nt][r] + bs + wl * eav[mt][r];
                    float s = v / (1.f + __expf(-v));
                    atomicAdd(&lgacc[(size_t)dstv[mt][r] * 128 + col], s);
                }
            }
    }
}

__global__ __launch_bounds__(256) void k_lg_final_r4(
    const float* __restrict__ lg_x, const float* __restrict__ edge_attr,
    const float* __restrict__ cnt,
    const float* __restrict__ g_edge, const float* __restrict__ beta_edge,
    float* __restrict__ out_lg, float* __restrict__ out_edge, int En)
{
    const int wave = threadIdx.x >> 6, lane = threadIdx.x & 63;
    const int e = blockIdx.x * 4 + wave;
    if (e >= En) return;
    const size_t base = (size_t)e * 128 + lane * 2;
    float2 accv = *(const float2*)&out_lg[base];
    float2 lgv  = *(const float2*)&lg_x[base];
    float inv = 1.f / fmaxf(cnt[e], 1.f);
    float2 lnew = make_float2(fmaf(accv.x, inv, lgv.x), fmaf(accv.y, inv, lgv.y));
    *(float2*)&out_lg[base] = lnew;
    float2 ea = *(const float2*)&edge_attr[base];
    float t0 = ea.x + lnew.x, t1 = ea.y + lnew.y;
    float s = t0 + t1, sq = t0 * t0 + t1 * t1;
    #pragma unroll
    for (int off = 32; off; off >>= 1) { s += __shfl_xor(s, off); sq += __shfl_xor(sq, off); }
    float mean = s * (1.f / 128.f);
    float var  = sq * (1.f / 128.f) - mean * mean;
    float r = rsqrtf(var + 1e-5f);
    int j0 = lane * 2;
    float o0 = (t0 - mean) * r * g_edge[j0]     + beta_edge[j0];
    float o1 = (t1 - mean) * r * g_edge[j0 + 1] + beta_edge[j0 + 1];
    *(float2*)&out_edge[base] = make_float2(o0, o1);
}

__global__ __launch_bounds__(256) void k_gate_atomic(
    const float* __restrict__ Ein, const short* __restrict__ Wp,
    const float* __restrict__ bg, const int* __restrict__ colidx,
    float* __restrict__ agg, int En)
{
    const int tid = threadIdx.x;
    const int ln = tid & 63, wv = tid >> 6;
    const int l15 = ln & 15, lhi = ln >> 4;
    const int eb = blockIdx.x * 128 + wv * 32;
    const s16x8* Bv = (const s16x8*)Wp;

    const float* rp[2];
    #pragma unroll
    for (int mt = 0; mt < 2; ++mt) {
        int e = eb + mt * 16 + l15;
        rp[mt] = Ein + (size_t)(e < En ? e : En - 1) * 128;
    }
    f32x4 acc[2][8];
    #pragma unroll
    for (int m = 0; m < 2; ++m)
        #pragma unroll
        for (int n = 0; n < 8; ++n) acc[m][n] = (f32x4){0.f, 0.f, 0.f, 0.f};
    #pragma unroll 2
    for (int kt = 0; kt < 4; ++kt) {
        int ko = kt * 32 + lhi * 8;
        s16x8 a[2];
        #pragma unroll
        for (int mt = 0; mt < 2; ++mt) {
            float buf[8];
            *(float4*)&buf[0] = *(const float4*)(rp[mt] + ko);
            *(float4*)&buf[4] = *(const float4*)(rp[mt] + ko + 4);
            a[mt] = pack8(buf);
        }
        const s16x8* brow = Bv + (size_t)(kt * 4 + lhi) * 128 + l15;
        #pragma unroll
        for (int nt = 0; nt < 8; ++nt) {
            s16x8 b = brow[nt * 16];
            acc[0][nt] = __builtin_amdgcn_mfma_f32_16x16x32_bf16(a[0], b, acc[0][nt], 0, 0, 0);
            acc[1][nt] = __builtin_amdgcn_mfma_f32_16x16x32_bf16(a[1], b, acc[1][nt], 0, 0, 0);
        }
    }
    int colv[2][4];
    #pragma unroll
    for (int mt = 0; mt < 2; ++mt)
        #pragma unroll
        for (int r = 0; r < 4; ++r) {
            int e = eb + mt * 16 + lhi * 4 + r;
            colv[mt][r] = colidx[e < En ? e : 0];
        }
    #pragma unroll
    for (int nt = 0; nt < 8; ++nt) {
        int col = nt * 16 + l15;
        float bs = bg[col];
        #pragma unroll
        for (int mt = 0; mt < 2; ++mt)
            #pragma unroll
            for (int r = 0; r < 4; ++r) {
                int e = eb + mt * 16 + lhi * 4 + r;
                if (e < En) {
                    float g = 1.f / (1.f + __expf(-(acc[mt][nt][r] + bs)));
                    float val = g * Ein[(size_t)e * 128 + col];
                    atomicAdd(&agg[(size_t)colv[mt][r] * 128 + col], val);
                }
            }
    }
}

// ---------------------------------------------------------------------------
extern "C" void kernel_launch(void* const* d_in, const int* in_sizes, int n_in,
                              void* d_out, int out_size, void* d_ws, size_t ws_size,
                              hipStream_t stream) {
    const float* x          = (const float*)d_in[0];
    const float* edge_attr  = (const float*)d_in[1];
    const float* lg_x       = (const float*)d_in[2];
    const float* lg_ea      = (const float*)d_in[3];
    const float* W_line     = (const float*)d_in[4];
    const float* b_line     = (const float*)d_in[5];
    const float* W_gate     = (const float*)d_in[6];
    const float* b_gate     = (const float*)d_in[7];
    const float* W_atom     = (const float*)d_in[8];
    const float* b_atom     = (const float*)d_in[9];
    const float* g_node     = (const float*)d_in[10];
    const float* beta_node  = (const float*)d_in[11];
    const float* g_edge     = (const float*)d_in[12];
    const float* beta_edge  = (const float*)d_in[13];
    const int*   edge_index    = (const int*)d_in[14];
    const int*   lg_edge_index = (const int*)d_in[15];

    const int Nn  = in_sizes[0] / 128;
    const int En  = in_sizes[1] / 128;
    const int LEn = in_sizes[3];

    float* out_x    = (float*)d_out;
    float* out_edge = out_x + (size_t)Nn * 128;
    float* out_lg   = out_edge + (size_t)En * 128;

    const int* lg_src = lg_edge_index;
    const int* lg_dst = lg_edge_index + LEn;
    const int* col    = edge_index + En;

    // weights
    short* wp_line = (short*)d_ws;            // 32768 shorts
    short* wp_gate = wp_line + 32768;         // 16384
    short* wp_atom = wp_gate + 16384;         // 32768

    // CSR-tier layout
    int* ip = (int*)(wp_atom + 32768);
    int* off_lg  = ip;  ip += En + 1;
    int* deg_lg  = ip;  ip += En + 1;
    int* cur_lg  = ip;  ip += En;
    int* perm_lg = ip;  ip += LEn;
    int* bsum_lg = ip;  ip += 1024;
    int* off_at  = ip;  ip += Nn + 1;
    int* deg_at  = ip;  ip += Nn + 1;
    int* cur_at  = ip;  ip += Nn;
    int* perm_at = ip;  ip += En;
    int* bsum_at = ip;  ip += 1024;
    short* lgx_bf = (short*)(((uintptr_t)ip + 15) & ~(uintptr_t)15);
    short* gated  = lgx_bf;   // reused after k_line_csr is done
    const size_t need_csr = ((uintptr_t)(lgx_bf + (size_t)En * 128)) - (uintptr_t)d_ws;

    if (ws_size >= need_csr) {
        // ---------------- CSR tier ----------------
        hipMemsetAsync(deg_lg, 0, (size_t)(En + 1) * 4, stream);
        hipMemsetAsync(cur_lg, 0, (size_t)En * 4, stream);
        hipMemsetAsync(deg_at, 0, (size_t)(Nn + 1) * 4, stream);
        hipMemsetAsync(cur_at, 0, (size_t)Nn * 4, stream);

        k_pack<<<16, 256, 0, stream>>>(W_line, wp_line, 4096);
        k_pack<<<8,  256, 0, stream>>>(W_gate, wp_gate, 2048);
        k_pack<<<16, 256, 0, stream>>>(W_atom, wp_atom, 4096);
        k_cvt<<<2048, 256, 0, stream>>>(lg_x, lgx_bf, (long)En * 16);

        k_hist<<<(LEn + 255) / 256, 256, 0, stream>>>(lg_dst, deg_lg, LEn);
        k_hist<<<(En + 255) / 256, 256, 0, stream>>>(col, deg_at, En);
        const int nb_lg = (En + SCAN_CHUNK - 1) / SCAN_CHUNK;
        const int nb_at = (Nn + SCAN_CHUNK - 1) / SCAN_CHUNK;
        k_scan_block<<<nb_lg, 256, 0, stream>>>(deg_lg, En, off_lg, bsum_lg);
        k_scan_block<<<nb_at, 256, 0, stream>>>(deg_at, Nn, off_at, bsum_at);
        k_scan_bsum<<<1, 64, 0, stream>>>(bsum_lg, nb_lg);
        k_scan_bsum<<<1, 64, 0, stream>>>(bsum_at, nb_at);
        k_scan_add<<<(En + 255) / 256, 256, 0, stream>>>(off_lg, bsum_lg, En, LEn);
        k_scan_add<<<(Nn + 255) / 256, 256, 0, stream>>>(off_at, bsum_at, Nn, En);
        k_fill<<<(LEn + 255) / 256, 256, 0, stream>>>(lg_dst, off_lg, cur_lg, perm_lg, LEn);
        k_fill<<<(En + 255) / 256, 256, 0, stream>>>(col, off_at, cur_at, perm_at, En);

        short* msg = (short*)out_edge;       // scratch inside d_out, overwritten by k_edge_ln
        k_line_csr<<<(LEn + 127) / 128, 256, 0, stream>>>(
            lgx_bf, lg_ea, wp_line, W_line, b_line, lg_src, lg_dst, msg, LEn);
        k_lg_gather<<<(En + 3) / 4, 256, 0, stream>>>(
            msg, lg_x, off_lg, perm_lg, out_lg, En);
        k_edge_ln<<<(En + 3) / 4, 256, 0, stream>>>(
            out_lg, edge_attr, g_edge, beta_edge, out_edge, En);
        k_gate_csr<<<(En + 127) / 128, 256, 0, stream>>>(
            out_edge, wp_gate, b_gate, gated, En);
        k_atom_gather<<<(Nn + 3) / 4, 256, 0, stream>>>(
            gated, off_at, perm_at, out_x, Nn);
        k_atom_mfma<<<(Nn + 127) / 128, 256, 0, stream>>>(
            x, out_x, wp_atom, b_atom, g_node, beta_node, out_x, Nn);
    } else {
        // ---------------- fallback: r4 atomic pipeline ----------------
        float* cnt = (float*)(wp_atom + 32768);
        short* lgx_bf2 = (short*)(((uintptr_t)(cnt + En) + 15) & ~(uintptr_t)15);
        const size_t need_bf = ((uintptr_t)(lgx_bf2 + (size_t)En * 128)) - (uintptr_t)d_ws;
        const bool use_bf = ws_size >= need_bf;

        hipMemsetAsync(out_x,  0, (size_t)Nn * 128 * sizeof(float), stream);
        hipMemsetAsync(out_lg, 0, (size_t)En * 128 * sizeof(float), stream);
        hipMemsetAsync(cnt,    0, (size_t)En * sizeof(float), stream);

        k_pack<<<16, 256, 0, stream>>>(W_line, wp_line, 4096);
        k_pack<<<8,  256, 0, stream>>>(W_gate, wp_gate, 2048);
        k_pack<<<16, 256, 0, stream>>>(W_atom, wp_atom, 4096);
        k_count<<<(LEn + 255) / 256, 256, 0, stream>>>(lg_dst, cnt, LEn);
        if (use_bf) {
            k_cvt<<<2048, 256, 0, stream>>>(lg_x, lgx_bf2, (long)En * 16);
            k_line_atomic<true><<<(LEn + 127) / 128, 256, 0, stream>>>(
                lg_x, lgx_bf2, lg_ea, wp_line, W_line, b_line, lg_src, lg_dst, out_lg, LEn);
        } else {
            k_line_atomic<false><<<(LEn + 127) / 128, 256, 0, stream>>>(
                lg_x, lgx_bf2, lg_ea, wp_line, W_line, b_line, lg_src, lg_dst, out_lg, LEn);
        }
        k_lg_final_r4<<<(En + 3) / 4, 256, 0, stream>>>(
            lg_x, edge_attr, cnt, g_edge, beta_edge, out_lg, out_edge, En);
        k_gate_atomic<<<(En + 127) / 128, 256, 0, stream>>>(
            out_edge, wp_gate, b_gate, col, out_x, En);
        k_atom_mfma<<<(Nn + 127) / 128, 256, 0, stream>>>(
            x, out_x, wp_atom, b_atom, g_node, beta_node, out_x, Nn);
    }
}

// Round 6
// 1640.078 us; speedup vs baseline: 1.7827x; 1.1322x over previous
//
#include <hip/hip_runtime.h>

// ---------------------------------------------------------------------------
// EdgeGatedConv — round 6: CSR position-scatter (write permuted, read contiguous).
//   r5 post-mortem: gathers of msg[perm[j]]/gated[perm[j]] were latency-bound
//   random reads. Now k_line/k_gate WRITE rows at pos[e]=off[seg]+rank, so the
//   segment reductions read contiguous ranges (pure streaming).
//   K1 k_line_csr:      GEMM -> msg bf16 row at pos_lg[e]   (msg in ws)
//   K2 k_lg_edge_fused: out_lg = lg_x + mean(msg[o0:o1]);
//                       out_edge = LN(edge_attr+out_lg); enew_bf = bf16(out_edge)
//   K3 k_gate_csr<BF>:  gate=sigmoid(enew@Wg+b); gated row at pos_at[e]
//   K3b k_atom_gather:  agg[n] = sum(gated[o0:o1])          (contiguous)
//   K4 k_atom_mfma:     h=silu([x,agg]@Wa+b); out_x = LN(x+h)
// Tier A (ws >= ~535MB): msg in ws, enew_bf active. Tier B (>=279MB, proven
// to fit in r5): msg in out_edge region, unfused gather+LN, gate reads fp32.
// MFMA 16x16x32 bf16: A row=lane&15, B col=lane&15, k=(lane>>4)*8+j both ops;
// C/D col=lane&15, row=(lane>>4)*4+reg.
// ---------------------------------------------------------------------------

typedef __attribute__((ext_vector_type(8))) short s16x8;
typedef __attribute__((ext_vector_type(4))) float f32x4;

#define SCAN_CHUNK 2048

__device__ __forceinline__ short f2bf(float f) {
    unsigned u = __float_as_uint(f);
    u += 0x7FFF + ((u >> 16) & 1);
    return (short)(u >> 16);
}
__device__ __forceinline__ float bf2f(unsigned short h) {
    return __uint_as_float(((unsigned)h) << 16);
}
__device__ __forceinline__ s16x8 pack8(const float* v) {
    s16x8 r;
    #pragma unroll
    for (int j = 0; j < 8; ++j) r[j] = f2bf(v[j]);
    return r;
}

// ---------------- prep ----------------
__global__ __launch_bounds__(256) void k_pack(const float* __restrict__ W,
                                              short* __restrict__ P, int nchunk) {
    int c = blockIdx.x * 256 + threadIdx.x;
    if (c >= nchunk) return;
    int g = c >> 7, col = c & 127, k0 = g * 8;
    s16x8 v;
    #pragma unroll
    for (int j = 0; j < 8; ++j) v[j] = f2bf(W[(size_t)(k0 + j) * 128 + col]);
    ((s16x8*)P)[c] = v;
}

__global__ __launch_bounds__(256) void k_cvt(const float* __restrict__ x,
                                             short* __restrict__ y, long n8) {
    long i = (long)blockIdx.x * 256 + threadIdx.x;
    const long stride = (long)gridDim.x * 256;
    for (; i < n8; i += stride) {
        float buf[8];
        *(float4*)&buf[0] = ((const float4*)x)[2 * i];
        *(float4*)&buf[4] = ((const float4*)x)[2 * i + 1];
        ((s16x8*)y)[i] = pack8(buf);
    }
}

// ---------------- CSR build ----------------
__global__ __launch_bounds__(256) void k_hist(const int* __restrict__ idx,
                                              int* __restrict__ deg, int n) {
    int i = blockIdx.x * 256 + threadIdx.x;
    if (i < n) atomicAdd(&deg[idx[i]], 1);
}

__global__ __launch_bounds__(256) void k_scan_block(const int* __restrict__ in, int n,
                                                    int* __restrict__ out,
                                                    int* __restrict__ bsum) {
    __shared__ int ts[256];
    const int b = blockIdx.x, t = threadIdx.x;
    const int base = b * SCAN_CHUNK + t * 8;
    int v[8]; int s = 0;
    #pragma unroll
    for (int i = 0; i < 8; ++i) { v[i] = (base + i < n) ? in[base + i] : 0; s += v[i]; }
    ts[t] = s;
    __syncthreads();
    int x = s;
    for (int off = 1; off < 256; off <<= 1) {
        int y = (t >= off) ? ts[t - off] : 0;
        __syncthreads();
        x += y; ts[t] = x;
        __syncthreads();
    }
    if (t == 255) bsum[b] = x;
    int run = x - s;
    #pragma unroll
    for (int i = 0; i < 8; ++i) {
        if (base + i < n) out[base + i] = run;
        run += v[i];
    }
}

__global__ void k_scan_bsum(int* __restrict__ bsum, int nb) {   // 1 wave
    const int lane = threadIdx.x;
    int carry = 0;
    for (int base = 0; base < nb; base += 64) {
        int i = base + lane;
        int v = (i < nb) ? bsum[i] : 0;
        int inc = v;
        #pragma unroll
        for (int off = 1; off < 64; off <<= 1) {
            int t = __shfl_up(inc, off);
            if (lane >= off) inc += t;
        }
        if (i < nb) bsum[i] = inc - v + carry;
        carry += __shfl(inc, 63);
    }
}

__global__ __launch_bounds__(256) void k_scan_add(int* __restrict__ off,
                                                  const int* __restrict__ bsum,
                                                  int n, int nedge) {
    int i = blockIdx.x * 256 + threadIdx.x;
    if (i < n) off[i] += bsum[i / SCAN_CHUNK];
    if (i == 0) off[n] = nedge;
}

// pos[i] = slot of element i inside its segment's CSR range
__global__ __launch_bounds__(256) void k_fill_pos(const int* __restrict__ idx,
                                                  const int* __restrict__ off,
                                                  int* __restrict__ cur,
                                                  int* __restrict__ pos, int n) {
    int i = blockIdx.x * 256 + threadIdx.x;
    if (i < n) {
        int s = idx[i];
        int p = atomicAdd(&cur[s], 1);
        pos[i] = off[s] + p;
    }
}

// ---------------- K1: line GEMM -> msg row at pos_lg[e] ----------------
__global__ __launch_bounds__(256) void k_line_csr(
    const short* __restrict__ lgx_bf, const float* __restrict__ lg_ea,
    const short* __restrict__ Wp, const float* __restrict__ W_line,
    const float* __restrict__ b_line,
    const int* __restrict__ lg_src, const int* __restrict__ lg_dst,
    const int* __restrict__ pos_lg,
    short* __restrict__ msg, int LEn)
{
    __shared__ __align__(16) short sh[128][136];
    const int tid = threadIdx.x;
    const int ln = tid & 63, wv = tid >> 6;
    const int l15 = ln & 15, lhi = ln >> 4;
    const int eb = blockIdx.x * 128 + wv * 32;
    const s16x8* Bv = (const s16x8*)Wp;

    const short *sp[2], *dp[2];
    #pragma unroll
    for (int mt = 0; mt < 2; ++mt) {
        int e = eb + mt * 16 + l15;
        int ec = e < LEn ? e : LEn - 1;
        sp[mt] = lgx_bf + (size_t)lg_src[ec] * 128;
        dp[mt] = lgx_bf + (size_t)lg_dst[ec] * 128;
    }

    f32x4 acc[2][8];
    #pragma unroll
    for (int m = 0; m < 2; ++m)
        #pragma unroll
        for (int n = 0; n < 8; ++n) acc[m][n] = (f32x4){0.f, 0.f, 0.f, 0.f};

    #pragma unroll 2
    for (int kt = 0; kt < 8; ++kt) {
        int ko = (kt & 3) * 32 + lhi * 8;
        s16x8 a[2];
        #pragma unroll
        for (int mt = 0; mt < 2; ++mt)
            a[mt] = *(const s16x8*)(((kt < 4) ? sp[mt] : dp[mt]) + ko);
        const s16x8* brow = Bv + (size_t)(kt * 4 + lhi) * 128 + l15;
        #pragma unroll
        for (int nt = 0; nt < 8; ++nt) {
            s16x8 b = brow[nt * 16];
            acc[0][nt] = __builtin_amdgcn_mfma_f32_16x16x32_bf16(a[0], b, acc[0][nt], 0, 0, 0);
            acc[1][nt] = __builtin_amdgcn_mfma_f32_16x16x32_bf16(a[1], b, acc[1][nt], 0, 0, 0);
        }
    }

    float eav[2][4];
    #pragma unroll
    for (int mt = 0; mt < 2; ++mt)
        #pragma unroll
        for (int r = 0; r < 4; ++r) {
            int e = eb + mt * 16 + lhi * 4 + r;
            eav[mt][r] = lg_ea[e < LEn ? e : 0];
        }

    #pragma unroll
    for (int nt = 0; nt < 8; ++nt) {
        int col = nt * 16 + l15;
        float wl = W_line[(size_t)256 * 128 + col];
        float bs = b_line[col];
        #pragma unroll
        for (int mt = 0; mt < 2; ++mt)
            #pragma unroll
            for (int r = 0; r < 4; ++r) {
                float v = acc[mt][nt][r] + bs + wl * eav[mt][r];
                float s = v / (1.f + __expf(-v));
                sh[wv * 32 + mt * 16 + lhi * 4 + r][col] = f2bf(s);
            }
    }
    __syncthreads();
    #pragma unroll
    for (int i = 0; i < 8; ++i) {
        int c = tid + i * 256;                 // 128 rows x 16 chunks
        int row = c >> 4, q = c & 15;
        int e = blockIdx.x * 128 + row;
        if (e < LEn) {
            int p = pos_lg[e];
            *(s16x8*)&msg[(size_t)p * 128 + q * 8] = *(const s16x8*)&sh[row][q * 8];
        }
    }
}

// ---------------- K2: fused contiguous gather-mean + residual + edge LN ----------------
__global__ __launch_bounds__(256) void k_lg_edge_fused(
    const short* __restrict__ msg, const float* __restrict__ lg_x,
    const float* __restrict__ edge_attr, const int* __restrict__ off,
    const float* __restrict__ g_edge, const float* __restrict__ beta_edge,
    float* __restrict__ out_lg, float* __restrict__ out_edge,
    short* __restrict__ enew_bf, int En)
{
    const int wave = threadIdx.x >> 6, lane = threadIdx.x & 63;
    const int e = blockIdx.x * 4 + wave;
    if (e >= En) return;
    const int o0 = off[e], o1 = off[e + 1];
    const int cnt = o1 - o0;
    const short* base = msg + (size_t)o0 * 128 + lane * 2;
    float s0 = 0.f, s1 = 0.f;
    int j = 0;
    for (; j + 1 < cnt; j += 2) {
        ushort2 u0 = *(const ushort2*)(base + (size_t)j * 128);
        ushort2 u1 = *(const ushort2*)(base + (size_t)(j + 1) * 128);
        s0 += bf2f(u0.x) + bf2f(u1.x);
        s1 += bf2f(u0.y) + bf2f(u1.y);
    }
    if (j < cnt) {
        ushort2 u = *(const ushort2*)(base + (size_t)j * 128);
        s0 += bf2f(u.x); s1 += bf2f(u.y);
    }
    const float inv = 1.f / fmaxf((float)cnt, 1.f);
    const size_t rb = (size_t)e * 128 + lane * 2;
    float2 lx = *(const float2*)&lg_x[rb];
    float l0 = fmaf(s0, inv, lx.x), l1 = fmaf(s1, inv, lx.y);
    *(float2*)&out_lg[rb] = make_float2(l0, l1);

    float2 ea = *(const float2*)&edge_attr[rb];
    float t0 = ea.x + l0, t1 = ea.y + l1;
    float s = t0 + t1, sq = t0 * t0 + t1 * t1;
    #pragma unroll
    for (int o = 32; o; o >>= 1) {
        s  += __shfl_xor(s, o);
        sq += __shfl_xor(sq, o);
    }
    float mean = s * (1.f / 128.f);
    float var  = sq * (1.f / 128.f) - mean * mean;
    float r = rsqrtf(var + 1e-5f);
    int j0 = lane * 2;
    float e0 = (t0 - mean) * r * g_edge[j0]     + beta_edge[j0];
    float e1 = (t1 - mean) * r * g_edge[j0 + 1] + beta_edge[j0 + 1];
    *(float2*)&out_edge[rb] = make_float2(e0, e1);
    if (enew_bf) {
        ushort2 ub = make_ushort2((unsigned short)f2bf(e0), (unsigned short)f2bf(e1));
        *(ushort2*)&enew_bf[rb] = ub;
    }
}

// ---------------- tier-B: unfused gather + LN ----------------
__global__ __launch_bounds__(256) void k_lg_gather(
    const short* __restrict__ msg, const float* __restrict__ lg_x,
    const int* __restrict__ off, float* __restrict__ out_lg, int En)
{
    const int wave = threadIdx.x >> 6, lane = threadIdx.x & 63;
    const int e = blockIdx.x * 4 + wave;
    if (e >= En) return;
    const int o0 = off[e], o1 = off[e + 1];
    const int cnt = o1 - o0;
    const short* base = msg + (size_t)o0 * 128 + lane * 2;
    float s0 = 0.f, s1 = 0.f;
    for (int j = 0; j < cnt; ++j) {
        ushort2 u = *(const ushort2*)(base + (size_t)j * 128);
        s0 += bf2f(u.x); s1 += bf2f(u.y);
    }
    const float inv = 1.f / fmaxf((float)cnt, 1.f);
    const size_t rb = (size_t)e * 128 + lane * 2;
    float2 lx = *(const float2*)&lg_x[rb];
    *(float2*)&out_lg[rb] = make_float2(fmaf(s0, inv, lx.x), fmaf(s1, inv, lx.y));
}

__global__ __launch_bounds__(256) void k_edge_ln(
    const float* __restrict__ lnew, const float* __restrict__ edge_attr,
    const float* __restrict__ g_edge, const float* __restrict__ beta_edge,
    float* __restrict__ out_edge, int En)
{
    const int wave = threadIdx.x >> 6, lane = threadIdx.x & 63;
    const int e = blockIdx.x * 4 + wave;
    if (e >= En) return;
    const size_t rb = (size_t)e * 128 + lane * 2;
    float2 lv = *(const float2*)&lnew[rb];
    float2 ea = *(const float2*)&edge_attr[rb];
    float t0 = ea.x + lv.x, t1 = ea.y + lv.y;
    float s = t0 + t1, sq = t0 * t0 + t1 * t1;
    #pragma unroll
    for (int o = 32; o; o >>= 1) { s += __shfl_xor(s, o); sq += __shfl_xor(sq, o); }
    float mean = s * (1.f / 128.f);
    float var  = sq * (1.f / 128.f) - mean * mean;
    float r = rsqrtf(var + 1e-5f);
    int j0 = lane * 2;
    float o0 = (t0 - mean) * r * g_edge[j0]     + beta_edge[j0];
    float o1 = (t1 - mean) * r * g_edge[j0 + 1] + beta_edge[j0 + 1];
    *(float2*)&out_edge[rb] = make_float2(o0, o1);
}

// ---------------- K3: gate GEMM -> gated row at pos_at[e] ----------------
template <bool BF>
__global__ __launch_bounds__(256) void k_gate_csr(
    const short* __restrict__ EinB, const float* __restrict__ EinF,
    const short* __restrict__ Wp, const float* __restrict__ bg,
    const int* __restrict__ pos_at, short* __restrict__ gated, int En)
{
    __shared__ __align__(16) short sh[128][136];
    const int tid = threadIdx.x;
    const int ln = tid & 63, wv = tid >> 6;
    const int l15 = ln & 15, lhi = ln >> 4;
    const int eb = blockIdx.x * 128 + wv * 32;
    const s16x8* Bv = (const s16x8*)Wp;

    int rowi[2];
    #pragma unroll
    for (int mt = 0; mt < 2; ++mt) {
        int e = eb + mt * 16 + l15;
        rowi[mt] = e < En ? e : En - 1;
    }

    f32x4 acc[2][8];
    #pragma unroll
    for (int m = 0; m < 2; ++m)
        #pragma unroll
        for (int n = 0; n < 8; ++n) acc[m][n] = (f32x4){0.f, 0.f, 0.f, 0.f};

    #pragma unroll 2
    for (int kt = 0; kt < 4; ++kt) {
        int ko = kt * 32 + lhi * 8;
        s16x8 a[2];
        #pragma unroll
        for (int mt = 0; mt < 2; ++mt) {
            if (BF) {
                a[mt] = *(const s16x8*)(EinB + (size_t)rowi[mt] * 128 + ko);
            } else {
                const float* p = EinF + (size_t)rowi[mt] * 128 + ko;
                float buf[8];
                *(float4*)&buf[0] = *(const float4*)p;
                *(float4*)&buf[4] = *(const float4*)(p + 4);
                a[mt] = pack8(buf);
            }
        }
        const s16x8* brow = Bv + (size_t)(kt * 4 + lhi) * 128 + l15;
        #pragma unroll
        for (int nt = 0; nt < 8; ++nt) {
            s16x8 b = brow[nt * 16];
            acc[0][nt] = __builtin_amdgcn_mfma_f32_16x16x32_bf16(a[0], b, acc[0][nt], 0, 0, 0);
            acc[1][nt] = __builtin_amdgcn_mfma_f32_16x16x32_bf16(a[1], b, acc[1][nt], 0, 0, 0);
        }
    }

    #pragma unroll
    for (int nt = 0; nt < 8; ++nt) {
        int col = nt * 16 + l15;
        float bs = bg[col];
        #pragma unroll
        for (int mt = 0; mt < 2; ++mt)
            #pragma unroll
            for (int r = 0; r < 4; ++r) {
                int e = eb + mt * 16 + lhi * 4 + r;
                int ec = e < En ? e : En - 1;
                float g = 1.f / (1.f + __expf(-(acc[mt][nt][r] + bs)));
                float ev = BF ? bf2f(((const unsigned short*)EinB)[(size_t)ec * 128 + col])
                              : EinF[(size_t)ec * 128 + col];
                sh[wv * 32 + mt * 16 + lhi * 4 + r][col] = f2bf(g * ev);
            }
    }
    __syncthreads();
    #pragma unroll
    for (int i = 0; i < 8; ++i) {
        int c = tid + i * 256;
        int row = c >> 4, q = c & 15;
        int e = blockIdx.x * 128 + row;
        if (e < En) {
            int p = pos_at[e];
            *(s16x8*)&gated[(size_t)p * 128 + q * 8] = *(const s16x8*)&sh[row][q * 8];
        }
    }
}

// ---------------- K3b: contiguous atom aggregation ----------------
__global__ __launch_bounds__(256) void k_atom_gather(
    const short* __restrict__ gated, const int* __restrict__ off,
    float* __restrict__ agg, int Nn)
{
    const int wave = threadIdx.x >> 6, lane = threadIdx.x & 63;
    const int n = blockIdx.x * 4 + wave;
    if (n >= Nn) return;
    const int o0 = off[n], o1 = off[n + 1];
    const int cnt = o1 - o0;
    const short* base = gated + (size_t)o0 * 128 + lane * 2;
    float s0 = 0.f, s1 = 0.f;
    int j = 0;
    for (; j + 1 < cnt; j += 2) {
        ushort2 u0 = *(const ushort2*)(base + (size_t)j * 128);
        ushort2 u1 = *(const ushort2*)(base + (size_t)(j + 1) * 128);
        s0 += bf2f(u0.x) + bf2f(u1.x);
        s1 += bf2f(u0.y) + bf2f(u1.y);
    }
    if (j < cnt) {
        ushort2 u = *(const ushort2*)(base + (size_t)j * 128);
        s0 += bf2f(u.x); s1 += bf2f(u.y);
    }
    *(float2*)&agg[(size_t)n * 128 + lane * 2] = make_float2(s0, s1);
}

// ---------------- K4: atom GEMM + residual + in-register LN ----------------
__global__ __launch_bounds__(256) void k_atom_mfma(
    const float* __restrict__ x, const float* __restrict__ aggin,
    const short* __restrict__ Wp, const float* __restrict__ ba,
    const float* __restrict__ gn, const float* __restrict__ bn,
    float* __restrict__ out, int Nn)
{
    const int tid = threadIdx.x;
    const int ln = tid & 63, wv = tid >> 6;
    const int l15 = ln & 15, lhi = ln >> 4;
    const int nb = blockIdx.x * 128 + wv * 32;
    const s16x8* Bv = (const s16x8*)Wp;

    const float *xp[2], *ap[2];
    #pragma unroll
    for (int mt = 0; mt < 2; ++mt) {
        int n = nb + mt * 16 + l15;
        size_t nc = (size_t)(n < Nn ? n : Nn - 1) * 128;
        xp[mt] = x + nc;
        ap[mt] = aggin + nc;
    }

    f32x4 acc[2][8];
    #pragma unroll
    for (int m = 0; m < 2; ++m)
        #pragma unroll
        for (int n = 0; n < 8; ++n) acc[m][n] = (f32x4){0.f, 0.f, 0.f, 0.f};

    #pragma unroll 2
    for (int kt = 0; kt < 8; ++kt) {
        int ko = (kt & 3) * 32 + lhi * 8;
        s16x8 a[2];
        #pragma unroll
        for (int mt = 0; mt < 2; ++mt) {
            const float* p = ((kt < 4) ? xp[mt] : ap[mt]) + ko;
            float buf[8];
            *(float4*)&buf[0] = *(const float4*)p;
            *(float4*)&buf[4] = *(const float4*)(p + 4);
            a[mt] = pack8(buf);
        }
        const s16x8* brow = Bv + (size_t)(kt * 4 + lhi) * 128 + l15;
        #pragma unroll
        for (int nt = 0; nt < 8; ++nt) {
            s16x8 b = brow[nt * 16];
            acc[0][nt] = __builtin_amdgcn_mfma_f32_16x16x32_bf16(a[0], b, acc[0][nt], 0, 0, 0);
            acc[1][nt] = __builtin_amdgcn_mfma_f32_16x16x32_bf16(a[1], b, acc[1][nt], 0, 0, 0);
        }
    }

    #pragma unroll
    for (int mt = 0; mt < 2; ++mt)
        #pragma unroll
        for (int r = 0; r < 4; ++r) {
            int n = nb + mt * 16 + lhi * 4 + r;
            size_t nr = (size_t)(n < Nn ? n : 0) * 128;
            float s = 0.f, sq = 0.f;
            #pragma unroll
            for (int nt = 0; nt < 8; ++nt) {
                int col = nt * 16 + l15;
                float v = acc[mt][nt][r] + ba[col];
                float h = v / (1.f + __expf(-v));
                float t = x[nr + col] + h;
                acc[mt][nt][r] = t;
                s += t; sq += t * t;
            }
            #pragma unroll
            for (int off = 8; off; off >>= 1) {
                s  += __shfl_xor(s, off);
                sq += __shfl_xor(sq, off);
            }
            float mean = s * (1.f / 128.f);
            float var  = sq * (1.f / 128.f) - mean * mean;
            float rstd = rsqrtf(var + 1e-5f);
            if (n < Nn) {
                #pragma unroll
                for (int nt = 0; nt < 8; ++nt) {
                    int col = nt * 16 + l15;
                    float o = (acc[mt][nt][r] - mean) * rstd * gn[col] + bn[col];
                    out[(size_t)n * 128 + col] = o;
                }
            }
        }
}

// ---------------------------------------------------------------------------
extern "C" void kernel_launch(void* const* d_in, const int* in_sizes, int n_in,
                              void* d_out, int out_size, void* d_ws, size_t ws_size,
                              hipStream_t stream) {
    const float* x          = (const float*)d_in[0];
    const float* edge_attr  = (const float*)d_in[1];
    const float* lg_x       = (const float*)d_in[2];
    const float* lg_ea      = (const float*)d_in[3];
    const float* W_line     = (const float*)d_in[4];
    const float* b_line     = (const float*)d_in[5];
    const float* W_gate     = (const float*)d_in[6];
    const float* b_gate     = (const float*)d_in[7];
    const float* W_atom     = (const float*)d_in[8];
    const float* b_atom     = (const float*)d_in[9];
    const float* g_node     = (const float*)d_in[10];
    const float* beta_node  = (const float*)d_in[11];
    const float* g_edge     = (const float*)d_in[12];
    const float* beta_edge  = (const float*)d_in[13];
    const int*   edge_index    = (const int*)d_in[14];
    const int*   lg_edge_index = (const int*)d_in[15];

    const int Nn  = in_sizes[0] / 128;
    const int En  = in_sizes[1] / 128;
    const int LEn = in_sizes[3];

    float* out_x    = (float*)d_out;
    float* out_edge = out_x + (size_t)Nn * 128;
    float* out_lg   = out_edge + (size_t)En * 128;

    const int* lg_src = lg_edge_index;
    const int* lg_dst = lg_edge_index + LEn;
    const int* col    = edge_index + En;

    // ws layout
    short* wp_line = (short*)d_ws;            // 32768 shorts
    short* wp_gate = wp_line + 32768;         // 16384
    short* wp_atom = wp_gate + 16384;         // 32768
    int* ip = (int*)(wp_atom + 32768);
    int* off_lg  = ip;  ip += En + 1;
    int* deg_lg  = ip;  ip += En;
    int* cur_lg  = ip;  ip += En;
    int* pos_lg  = ip;  ip += LEn;
    int* bsum_lg = ip;  ip += 1024;
    int* off_at  = ip;  ip += Nn + 1;
    int* deg_at  = ip;  ip += Nn;
    int* cur_at  = ip;  ip += Nn;
    int* pos_at  = ip;  ip += En;
    int* bsum_at = ip;  ip += 1024;
    short* lgx_bf = (short*)(((uintptr_t)ip + 15) & ~(uintptr_t)15);
    short* bufA   = lgx_bf + (size_t)En * 128;       // tier-A msg/gated (256 MB)
    const size_t need_B = ((uintptr_t)bufA) - (uintptr_t)d_ws;
    const size_t need_A = need_B + (size_t)En * 128 * 2;
    const bool tierA = ws_size >= need_A;

    hipMemsetAsync(deg_lg, 0, (size_t)En * 4, stream);
    hipMemsetAsync(cur_lg, 0, (size_t)En * 4, stream);
    hipMemsetAsync(deg_at, 0, (size_t)Nn * 4, stream);
    hipMemsetAsync(cur_at, 0, (size_t)Nn * 4, stream);

    k_pack<<<16, 256, 0, stream>>>(W_line, wp_line, 4096);
    k_pack<<<8,  256, 0, stream>>>(W_gate, wp_gate, 2048);
    k_pack<<<16, 256, 0, stream>>>(W_atom, wp_atom, 4096);
    k_cvt<<<2048, 256, 0, stream>>>(lg_x, lgx_bf, (long)En * 16);

    k_hist<<<(LEn + 255) / 256, 256, 0, stream>>>(lg_dst, deg_lg, LEn);
    k_hist<<<(En + 255) / 256, 256, 0, stream>>>(col, deg_at, En);
    const int nb_lg = (En + SCAN_CHUNK - 1) / SCAN_CHUNK;
    const int nb_at = (Nn + SCAN_CHUNK - 1) / SCAN_CHUNK;
    k_scan_block<<<nb_lg, 256, 0, stream>>>(deg_lg, En, off_lg, bsum_lg);
    k_scan_block<<<nb_at, 256, 0, stream>>>(deg_at, Nn, off_at, bsum_at);
    k_scan_bsum<<<1, 64, 0, stream>>>(bsum_lg, nb_lg);
    k_scan_bsum<<<1, 64, 0, stream>>>(bsum_at, nb_at);
    k_scan_add<<<(En + 255) / 256, 256, 0, stream>>>(off_lg, bsum_lg, En, LEn);
    k_scan_add<<<(Nn + 255) / 256, 256, 0, stream>>>(off_at, bsum_at, Nn, En);
    k_fill_pos<<<(LEn + 255) / 256, 256, 0, stream>>>(lg_dst, off_lg, cur_lg, pos_lg, LEn);
    k_fill_pos<<<(En + 255) / 256, 256, 0, stream>>>(col, off_at, cur_at, pos_at, En);

    if (tierA) {
        short* msg = bufA;
        k_line_csr<<<(LEn + 127) / 128, 256, 0, stream>>>(
            lgx_bf, lg_ea, wp_line, W_line, b_line, lg_src, lg_dst, pos_lg, msg, LEn);
        short* enew_bf = lgx_bf;             // lgx_bf dead after k_line_csr
        k_lg_edge_fused<<<(En + 3) / 4, 256, 0, stream>>>(
            msg, lg_x, edge_attr, off_lg, g_edge, beta_edge,
            out_lg, out_edge, enew_bf, En);
        short* gated = bufA;                 // msg dead after fused gather
        k_gate_csr<true><<<(En + 127) / 128, 256, 0, stream>>>(
            enew_bf, nullptr, wp_gate, b_gate, pos_at, gated, En);
        k_atom_gather<<<(Nn + 3) / 4, 256, 0, stream>>>(gated, off_at, out_x, Nn);
    } else {
        short* msg = (short*)out_edge;       // scratch in d_out, overwritten by k_edge_ln
        k_line_csr<<<(LEn + 127) / 128, 256, 0, stream>>>(
            lgx_bf, lg_ea, wp_line, W_line, b_line, lg_src, lg_dst, pos_lg, msg, LEn);
        k_lg_gather<<<(En + 3) / 4, 256, 0, stream>>>(msg, lg_x, off_lg, out_lg, En);
        k_edge_ln<<<(En + 3) / 4, 256, 0, stream>>>(
            out_lg, edge_attr, g_edge, beta_edge, out_edge, En);
        short* gated = lgx_bf;               // lgx_bf dead
        k_gate_csr<false><<<(En + 127) / 128, 256, 0, stream>>>(
            nullptr, out_edge, wp_gate, b_gate, pos_at, gated, En);
        k_atom_gather<<<(Nn + 3) / 4, 256, 0, stream>>>(gated, off_at, out_x, Nn);
    }
    k_atom_mfma<<<(Nn + 127) / 128, 256, 0, stream>>>(
        x, out_x, wp_atom, b_atom, g_node, beta_node, out_x, Nn);
}

// Round 7
// 1536.046 us; speedup vs baseline: 1.9034x; 1.0677x over previous
//
#include <hip/hip_runtime.h>

// ---------------------------------------------------------------------------
// EdgeGatedConv — round 7: traffic + launch consolidation on the r6 CSR design.
//   r6 post-mortem: pipeline ~5.4GB streaming, floor ~870µs, measured 1640 —
//   slack = fp32 re-reads, 8B/lane loads, 21 serialized dispatches.
//   Changes: fused kernel residual from bf16 lgx_bf (-256MB), 2 edges/wave @
//   16B/lane; agg in bf16 (-153MB, direct s16x8 A-frags); prep kernels merged.
//   K1 k_line_csr:      GEMM -> msg bf16 row at pos_lg[e]   (msg in ws)
//   K2 k_lg_edge_fused: out_lg = bf(lg_x) + mean(msg[o0:o1]);
//                       out_edge = LN(edge_attr+out_lg); enew_bf = bf16(out_edge)
//   K3 k_gate_csr<BF>:  gate=sigmoid(enew@Wg+b); gated row at pos_at[e]
//   K3b k_atom_gather:  agg_bf[n] = sum(gated[o0:o1])       (contiguous, bf16)
//   K4 k_atom_mfma:     h=silu([x,agg]@Wa+b); out_x = LN(x+h)
// MFMA 16x16x32 bf16: A row=lane&15, B col=lane&15, k=(lane>>4)*8+j both ops;
// C/D col=lane&15, row=(lane>>4)*4+reg.
// ---------------------------------------------------------------------------

typedef __attribute__((ext_vector_type(8))) short s16x8;
typedef __attribute__((ext_vector_type(4))) float f32x4;

#define SCAN_CHUNK 2048

__device__ __forceinline__ short f2bf(float f) {
    unsigned u = __float_as_uint(f);
    u += 0x7FFF + ((u >> 16) & 1);
    return (short)(u >> 16);
}
__device__ __forceinline__ float bf2f(unsigned short h) {
    return __uint_as_float(((unsigned)h) << 16);
}
__device__ __forceinline__ s16x8 pack8(const float* v) {
    s16x8 r;
    #pragma unroll
    for (int j = 0; j < 8; ++j) r[j] = f2bf(v[j]);
    return r;
}

// ---------------- prep: pack all three weights in one kernel ----------------
__global__ __launch_bounds__(256) void k_pack3(
    const float* __restrict__ Wl, const float* __restrict__ Wg,
    const float* __restrict__ Wa,
    short* __restrict__ Pl, short* __restrict__ Pg, short* __restrict__ Pa)
{
    int c = blockIdx.x * 256 + threadIdx.x;      // 0..10239
    const float* W; short* P; int cc;
    if (c < 4096)       { W = Wl; P = Pl; cc = c; }
    else if (c < 6144)  { W = Wg; P = Pg; cc = c - 4096; }
    else if (c < 10240) { W = Wa; P = Pa; cc = c - 6144; }
    else return;
    int g = cc >> 7, col = cc & 127, k0 = g * 8;
    s16x8 v;
    #pragma unroll
    for (int j = 0; j < 8; ++j) v[j] = f2bf(W[(size_t)(k0 + j) * 128 + col]);
    ((s16x8*)P)[cc] = v;
}

__global__ __launch_bounds__(256) void k_cvt(const float* __restrict__ x,
                                             short* __restrict__ y, long n8) {
    long i = (long)blockIdx.x * 256 + threadIdx.x;
    const long stride = (long)gridDim.x * 256;
    for (; i < n8; i += stride) {
        float buf[8];
        *(float4*)&buf[0] = ((const float4*)x)[2 * i];
        *(float4*)&buf[4] = ((const float4*)x)[2 * i + 1];
        ((s16x8*)y)[i] = pack8(buf);
    }
}

// ---------------- CSR build (dual graphs per kernel) ----------------
__global__ __launch_bounds__(256) void k_hist2(
    const int* __restrict__ idx1, int* __restrict__ deg1, int n1,
    const int* __restrict__ idx2, int* __restrict__ deg2, int n2)
{
    int i = blockIdx.x * 256 + threadIdx.x;
    if (i < n1) atomicAdd(&deg1[idx1[i]], 1);
    if (i < n2) atomicAdd(&deg2[idx2[i]], 1);
}

__global__ __launch_bounds__(256) void k_scan_block2(
    const int* __restrict__ in1, int n1, int* __restrict__ out1, int* __restrict__ bsum1, int nb1,
    const int* __restrict__ in2, int n2, int* __restrict__ out2, int* __restrict__ bsum2)
{
    __shared__ int ts[256];
    int b = blockIdx.x;
    const int* in; int n; int* out; int* bsum;
    if (b < nb1) { in = in1; n = n1; out = out1; bsum = bsum1; }
    else         { in = in2; n = n2; out = out2; bsum = bsum2; b -= nb1; }
    const int t = threadIdx.x;
    const int base = b * SCAN_CHUNK + t * 8;
    int v[8]; int s = 0;
    #pragma unroll
    for (int i = 0; i < 8; ++i) { v[i] = (base + i < n) ? in[base + i] : 0; s += v[i]; }
    ts[t] = s;
    __syncthreads();
    int x = s;
    for (int off = 1; off < 256; off <<= 1) {
        int y = (t >= off) ? ts[t - off] : 0;
        __syncthreads();
        x += y; ts[t] = x;
        __syncthreads();
    }
    if (t == 255) bsum[b] = x;
    int run = x - s;
    #pragma unroll
    for (int i = 0; i < 8; ++i) {
        if (base + i < n) out[base + i] = run;
        run += v[i];
    }
}

__global__ void k_scan_bsum2(int* __restrict__ b1, int nb1,
                             int* __restrict__ b2, int nb2) {  // 128 thr = 2 waves
    const int lane = threadIdx.x & 63;
    int* bsum = (threadIdx.x < 64) ? b1 : b2;
    const int nb  = (threadIdx.x < 64) ? nb1 : nb2;
    int carry = 0;
    for (int base = 0; base < nb; base += 64) {
        int i = base + lane;
        int v = (i < nb) ? bsum[i] : 0;
        int inc = v;
        #pragma unroll
        for (int off = 1; off < 64; off <<= 1) {
            int t = __shfl_up(inc, off);
            if (lane >= off) inc += t;
        }
        if (i < nb) bsum[i] = inc - v + carry;
        carry += __shfl(inc, 63);
    }
}

__global__ __launch_bounds__(256) void k_scan_add2(
    int* __restrict__ off1, const int* __restrict__ bsum1, int n1, int ne1,
    int* __restrict__ off2, const int* __restrict__ bsum2, int n2, int ne2)
{
    int i = blockIdx.x * 256 + threadIdx.x;
    if (i < n1) off1[i] += bsum1[i / SCAN_CHUNK];
    if (i < n2) off2[i] += bsum2[i / SCAN_CHUNK];
    if (i == 0) { off1[n1] = ne1; off2[n2] = ne2; }
}

__global__ __launch_bounds__(256) void k_fill_pos2(
    const int* __restrict__ idx1, const int* __restrict__ off1,
    int* __restrict__ cur1, int* __restrict__ pos1, int n1,
    const int* __restrict__ idx2, const int* __restrict__ off2,
    int* __restrict__ cur2, int* __restrict__ pos2, int n2)
{
    int i = blockIdx.x * 256 + threadIdx.x;
    if (i < n1) {
        int s = idx1[i];
        int p = atomicAdd(&cur1[s], 1);
        pos1[i] = off1[s] + p;
    }
    if (i < n2) {
        int s = idx2[i];
        int p = atomicAdd(&cur2[s], 1);
        pos2[i] = off2[s] + p;
    }
}

// ---------------- K1: line GEMM -> msg row at pos_lg[e] ----------------
__global__ __launch_bounds__(256) void k_line_csr(
    const short* __restrict__ lgx_bf, const float* __restrict__ lg_ea,
    const short* __restrict__ Wp, const float* __restrict__ W_line,
    const float* __restrict__ b_line,
    const int* __restrict__ lg_src, const int* __restrict__ lg_dst,
    const int* __restrict__ pos_lg,
    short* __restrict__ msg, int LEn)
{
    __shared__ __align__(16) short sh[128][136];
    const int tid = threadIdx.x;
    const int ln = tid & 63, wv = tid >> 6;
    const int l15 = ln & 15, lhi = ln >> 4;
    const int eb = blockIdx.x * 128 + wv * 32;
    const s16x8* Bv = (const s16x8*)Wp;

    const short *sp[2], *dp[2];
    #pragma unroll
    for (int mt = 0; mt < 2; ++mt) {
        int e = eb + mt * 16 + l15;
        int ec = e < LEn ? e : LEn - 1;
        sp[mt] = lgx_bf + (size_t)lg_src[ec] * 128;
        dp[mt] = lgx_bf + (size_t)lg_dst[ec] * 128;
    }

    f32x4 acc[2][8];
    #pragma unroll
    for (int m = 0; m < 2; ++m)
        #pragma unroll
        for (int n = 0; n < 8; ++n) acc[m][n] = (f32x4){0.f, 0.f, 0.f, 0.f};

    #pragma unroll 2
    for (int kt = 0; kt < 8; ++kt) {
        int ko = (kt & 3) * 32 + lhi * 8;
        s16x8 a[2];
        #pragma unroll
        for (int mt = 0; mt < 2; ++mt)
            a[mt] = *(const s16x8*)(((kt < 4) ? sp[mt] : dp[mt]) + ko);
        const s16x8* brow = Bv + (size_t)(kt * 4 + lhi) * 128 + l15;
        #pragma unroll
        for (int nt = 0; nt < 8; ++nt) {
            s16x8 b = brow[nt * 16];
            acc[0][nt] = __builtin_amdgcn_mfma_f32_16x16x32_bf16(a[0], b, acc[0][nt], 0, 0, 0);
            acc[1][nt] = __builtin_amdgcn_mfma_f32_16x16x32_bf16(a[1], b, acc[1][nt], 0, 0, 0);
        }
    }

    float eav[2][4];
    #pragma unroll
    for (int mt = 0; mt < 2; ++mt)
        #pragma unroll
        for (int r = 0; r < 4; ++r) {
            int e = eb + mt * 16 + lhi * 4 + r;
            eav[mt][r] = lg_ea[e < LEn ? e : 0];
        }

    #pragma unroll
    for (int nt = 0; nt < 8; ++nt) {
        int col = nt * 16 + l15;
        float wl = W_line[(size_t)256 * 128 + col];
        float bs = b_line[col];
        #pragma unroll
        for (int mt = 0; mt < 2; ++mt)
            #pragma unroll
            for (int r = 0; r < 4; ++r) {
                float v = acc[mt][nt][r] + bs + wl * eav[mt][r];
                float s = v / (1.f + __expf(-v));
                sh[wv * 32 + mt * 16 + lhi * 4 + r][col] = f2bf(s);
            }
    }
    __syncthreads();
    #pragma unroll
    for (int i = 0; i < 8; ++i) {
        int c = tid + i * 256;                 // 128 rows x 16 chunks
        int row = c >> 4, q = c & 15;
        int e = blockIdx.x * 128 + row;
        if (e < LEn) {
            int p = pos_lg[e];
            *(s16x8*)&msg[(size_t)p * 128 + q * 8] = *(const s16x8*)&sh[row][q * 8];
        }
    }
}

// ---------------- K2: fused gather-mean + residual + edge LN (2 edges/wave) ----------------
__global__ __launch_bounds__(256) void k_lg_edge_fused(
    const short* __restrict__ msg, const short* __restrict__ lgx_bf,
    const float* __restrict__ edge_attr, const int* __restrict__ off,
    const float* __restrict__ g_edge, const float* __restrict__ beta_edge,
    float* __restrict__ out_lg, float* __restrict__ out_edge,
    short* __restrict__ enew_bf, int En)
{
    const int wave = threadIdx.x >> 6, lane = threadIdx.x & 63;
    const int half = lane >> 5, l = lane & 31;
    const int e = blockIdx.x * 8 + wave * 2 + half;
    if (e >= En) return;
    const int o0 = off[e], o1 = off[e + 1];
    const int cnt = o1 - o0;
    const short* mbase = msg + (size_t)o0 * 128 + l * 4;
    float s0 = 0.f, s1 = 0.f, s2 = 0.f, s3 = 0.f;
    for (int j = 0; j < cnt; ++j) {
        ushort4 u = *(const ushort4*)(mbase + (size_t)j * 128);
        s0 += bf2f(u.x); s1 += bf2f(u.y); s2 += bf2f(u.z); s3 += bf2f(u.w);
    }
    const float inv = 1.f / fmaxf((float)cnt, 1.f);
    const size_t rb = (size_t)e * 128 + l * 4;
    ushort4 lxu = *(const ushort4*)&lgx_bf[rb];
    float l0 = fmaf(s0, inv, bf2f(lxu.x));
    float l1 = fmaf(s1, inv, bf2f(lxu.y));
    float l2 = fmaf(s2, inv, bf2f(lxu.z));
    float l3 = fmaf(s3, inv, bf2f(lxu.w));
    *(float4*)&out_lg[rb] = make_float4(l0, l1, l2, l3);

    float4 ea = *(const float4*)&edge_attr[rb];
    float t0 = ea.x + l0, t1 = ea.y + l1, t2 = ea.z + l2, t3 = ea.w + l3;
    float s = t0 + t1 + t2 + t3;
    float sq = t0 * t0 + t1 * t1 + t2 * t2 + t3 * t3;
    #pragma unroll
    for (int o = 16; o; o >>= 1) {             // reduce within 32-lane half
        s  += __shfl_xor(s, o);
        sq += __shfl_xor(sq, o);
    }
    float mean = s * (1.f / 128.f);
    float var  = sq * (1.f / 128.f) - mean * mean;
    float r = rsqrtf(var + 1e-5f);
    int j0 = l * 4;
    float4 gg = *(const float4*)&g_edge[j0];
    float4 bb = *(const float4*)&beta_edge[j0];
    float e0 = fmaf((t0 - mean) * r, gg.x, bb.x);
    float e1 = fmaf((t1 - mean) * r, gg.y, bb.y);
    float e2 = fmaf((t2 - mean) * r, gg.z, bb.z);
    float e3 = fmaf((t3 - mean) * r, gg.w, bb.w);
    *(float4*)&out_edge[rb] = make_float4(e0, e1, e2, e3);
    if (enew_bf) {
        ushort4 ub = make_ushort4((unsigned short)f2bf(e0), (unsigned short)f2bf(e1),
                                  (unsigned short)f2bf(e2), (unsigned short)f2bf(e3));
        *(ushort4*)&enew_bf[rb] = ub;
    }
}

// ---------------- tier-B: unfused gather + LN ----------------
__global__ __launch_bounds__(256) void k_lg_gather(
    const short* __restrict__ msg, const float* __restrict__ lg_x,
    const int* __restrict__ off, float* __restrict__ out_lg, int En)
{
    const int wave = threadIdx.x >> 6, lane = threadIdx.x & 63;
    const int e = blockIdx.x * 4 + wave;
    if (e >= En) return;
    const int o0 = off[e], o1 = off[e + 1];
    const int cnt = o1 - o0;
    const short* base = msg + (size_t)o0 * 128 + lane * 2;
    float s0 = 0.f, s1 = 0.f;
    for (int j = 0; j < cnt; ++j) {
        ushort2 u = *(const ushort2*)(base + (size_t)j * 128);
        s0 += bf2f(u.x); s1 += bf2f(u.y);
    }
    const float inv = 1.f / fmaxf((float)cnt, 1.f);
    const size_t rb = (size_t)e * 128 + lane * 2;
    float2 lx = *(const float2*)&lg_x[rb];
    *(float2*)&out_lg[rb] = make_float2(fmaf(s0, inv, lx.x), fmaf(s1, inv, lx.y));
}

__global__ __launch_bounds__(256) void k_edge_ln(
    const float* __restrict__ lnew, const float* __restrict__ edge_attr,
    const float* __restrict__ g_edge, const float* __restrict__ beta_edge,
    float* __restrict__ out_edge, int En)
{
    const int wave = threadIdx.x >> 6, lane = threadIdx.x & 63;
    const int e = blockIdx.x * 4 + wave;
    if (e >= En) return;
    const size_t rb = (size_t)e * 128 + lane * 2;
    float2 lv = *(const float2*)&lnew[rb];
    float2 ea = *(const float2*)&edge_attr[rb];
    float t0 = ea.x + lv.x, t1 = ea.y + lv.y;
    float s = t0 + t1, sq = t0 * t0 + t1 * t1;
    #pragma unroll
    for (int o = 32; o; o >>= 1) { s += __shfl_xor(s, o); sq += __shfl_xor(sq, o); }
    float mean = s * (1.f / 128.f);
    float var  = sq * (1.f / 128.f) - mean * mean;
    float r = rsqrtf(var + 1e-5f);
    int j0 = lane * 2;
    float o0 = (t0 - mean) * r * g_edge[j0]     + beta_edge[j0];
    float o1 = (t1 - mean) * r * g_edge[j0 + 1] + beta_edge[j0 + 1];
    *(float2*)&out_edge[rb] = make_float2(o0, o1);
}

// ---------------- K3: gate GEMM -> gated row at pos_at[e] ----------------
template <bool BF>
__global__ __launch_bounds__(256) void k_gate_csr(
    const short* __restrict__ EinB, const float* __restrict__ EinF,
    const short* __restrict__ Wp, const float* __restrict__ bg,
    const int* __restrict__ pos_at, short* __restrict__ gated, int En)
{
    __shared__ __align__(16) short sh[128][136];
    const int tid = threadIdx.x;
    const int ln = tid & 63, wv = tid >> 6;
    const int l15 = ln & 15, lhi = ln >> 4;
    const int eb = blockIdx.x * 128 + wv * 32;
    const s16x8* Bv = (const s16x8*)Wp;

    int rowi[2];
    #pragma unroll
    for (int mt = 0; mt < 2; ++mt) {
        int e = eb + mt * 16 + l15;
        rowi[mt] = e < En ? e : En - 1;
    }

    f32x4 acc[2][8];
    #pragma unroll
    for (int m = 0; m < 2; ++m)
        #pragma unroll
        for (int n = 0; n < 8; ++n) acc[m][n] = (f32x4){0.f, 0.f, 0.f, 0.f};

    #pragma unroll 2
    for (int kt = 0; kt < 4; ++kt) {
        int ko = kt * 32 + lhi * 8;
        s16x8 a[2];
        #pragma unroll
        for (int mt = 0; mt < 2; ++mt) {
            if (BF) {
                a[mt] = *(const s16x8*)(EinB + (size_t)rowi[mt] * 128 + ko);
            } else {
                const float* p = EinF + (size_t)rowi[mt] * 128 + ko;
                float buf[8];
                *(float4*)&buf[0] = *(const float4*)p;
                *(float4*)&buf[4] = *(const float4*)(p + 4);
                a[mt] = pack8(buf);
            }
        }
        const s16x8* brow = Bv + (size_t)(kt * 4 + lhi) * 128 + l15;
        #pragma unroll
        for (int nt = 0; nt < 8; ++nt) {
            s16x8 b = brow[nt * 16];
            acc[0][nt] = __builtin_amdgcn_mfma_f32_16x16x32_bf16(a[0], b, acc[0][nt], 0, 0, 0);
            acc[1][nt] = __builtin_amdgcn_mfma_f32_16x16x32_bf16(a[1], b, acc[1][nt], 0, 0, 0);
        }
    }

    #pragma unroll
    for (int nt = 0; nt < 8; ++nt) {
        int col = nt * 16 + l15;
        float bs = bg[col];
        #pragma unroll
        for (int mt = 0; mt < 2; ++mt)
            #pragma unroll
            for (int r = 0; r < 4; ++r) {
                int e = eb + mt * 16 + lhi * 4 + r;
                int ec = e < En ? e : En - 1;
                float g = 1.f / (1.f + __expf(-(acc[mt][nt][r] + bs)));
                float ev = BF ? bf2f(((const unsigned short*)EinB)[(size_t)ec * 128 + col])
                              : EinF[(size_t)ec * 128 + col];
                sh[wv * 32 + mt * 16 + lhi * 4 + r][col] = f2bf(g * ev);
            }
    }
    __syncthreads();
    #pragma unroll
    for (int i = 0; i < 8; ++i) {
        int c = tid + i * 256;
        int row = c >> 4, q = c & 15;
        int e = blockIdx.x * 128 + row;
        if (e < En) {
            int p = pos_at[e];
            *(s16x8*)&gated[(size_t)p * 128 + q * 8] = *(const s16x8*)&sh[row][q * 8];
        }
    }
}

// ---------------- K3b: contiguous atom aggregation (2 nodes/wave) ----------------
template <bool BF_OUT>
__global__ __launch_bounds__(256) void k_atom_gather(
    const short* __restrict__ gated, const int* __restrict__ off,
    float* __restrict__ aggf, short* __restrict__ aggb, int Nn)
{
    const int wave = threadIdx.x >> 6, lane = threadIdx.x & 63;
    const int half = lane >> 5, l = lane & 31;
    const int n = blockIdx.x * 8 + wave * 2 + half;
    if (n >= Nn) return;
    const int o0 = off[n], o1 = off[n + 1];
    const int cnt = o1 - o0;
    const short* base = gated + (size_t)o0 * 128 + l * 4;
    float s0 = 0.f, s1 = 0.f, s2 = 0.f, s3 = 0.f;
    for (int j = 0; j < cnt; ++j) {
        ushort4 u = *(const ushort4*)(base + (size_t)j * 128);
        s0 += bf2f(u.x); s1 += bf2f(u.y); s2 += bf2f(u.z); s3 += bf2f(u.w);
    }
    const size_t rb = (size_t)n * 128 + l * 4;
    if (BF_OUT) {
        ushort4 ub = make_ushort4((unsigned short)f2bf(s0), (unsigned short)f2bf(s1),
                                  (unsigned short)f2bf(s2), (unsigned short)f2bf(s3));
        *(ushort4*)&aggb[rb] = ub;
    } else {
        *(float4*)&aggf[rb] = make_float4(s0, s1, s2, s3);
    }
}

// ---------------- K4: atom GEMM + residual + in-register LN ----------------
template <bool AGGBF>
__global__ __launch_bounds__(256) void k_atom_mfma(
    const float* __restrict__ x, const float* __restrict__ aggf,
    const short* __restrict__ aggb,
    const short* __restrict__ Wp, const float* __restrict__ ba,
    const float* __restrict__ gn, const float* __restrict__ bn,
    float* __restrict__ out, int Nn)
{
    const int tid = threadIdx.x;
    const int ln = tid & 63, wv = tid >> 6;
    const int l15 = ln & 15, lhi = ln >> 4;
    const int nb = blockIdx.x * 128 + wv * 32;
    const s16x8* Bv = (const s16x8*)Wp;

    const float* xp[2];
    size_t nc[2];
    #pragma unroll
    for (int mt = 0; mt < 2; ++mt) {
        int n = nb + mt * 16 + l15;
        nc[mt] = (size_t)(n < Nn ? n : Nn - 1) * 128;
        xp[mt] = x + nc[mt];
    }

    f32x4 acc[2][8];
    #pragma unroll
    for (int m = 0; m < 2; ++m)
        #pragma unroll
        for (int n = 0; n < 8; ++n) acc[m][n] = (f32x4){0.f, 0.f, 0.f, 0.f};

    #pragma unroll 2
    for (int kt = 0; kt < 8; ++kt) {
        int ko = (kt & 3) * 32 + lhi * 8;
        s16x8 a[2];
        #pragma unroll
        for (int mt = 0; mt < 2; ++mt) {
            if (kt < 4) {
                const float* p = xp[mt] + ko;
                float buf[8];
                *(float4*)&buf[0] = *(const float4*)p;
                *(float4*)&buf[4] = *(const float4*)(p + 4);
                a[mt] = pack8(buf);
            } else if (AGGBF) {
                a[mt] = *(const s16x8*)(aggb + nc[mt] + ko);
            } else {
                const float* p = aggf + nc[mt] + ko;
                float buf[8];
                *(float4*)&buf[0] = *(const float4*)p;
                *(float4*)&buf[4] = *(const float4*)(p + 4);
                a[mt] = pack8(buf);
            }
        }
        const s16x8* brow = Bv + (size_t)(kt * 4 + lhi) * 128 + l15;
        #pragma unroll
        for (int nt = 0; nt < 8; ++nt) {
            s16x8 b = brow[nt * 16];
            acc[0][nt] = __builtin_amdgcn_mfma_f32_16x16x32_bf16(a[0], b, acc[0][nt], 0, 0, 0);
            acc[1][nt] = __builtin_amdgcn_mfma_f32_16x16x32_bf16(a[1], b, acc[1][nt], 0, 0, 0);
        }
    }

    #pragma unroll
    for (int mt = 0; mt < 2; ++mt)
        #pragma unroll
        for (int r = 0; r < 4; ++r) {
            int n = nb + mt * 16 + lhi * 4 + r;
            size_t nr = (size_t)(n < Nn ? n : 0) * 128;
            float s = 0.f, sq = 0.f;
            #pragma unroll
            for (int nt = 0; nt < 8; ++nt) {
                int col = nt * 16 + l15;
                float v = acc[mt][nt][r] + ba[col];
                float h = v / (1.f + __expf(-v));
                float t = x[nr + col] + h;
                acc[mt][nt][r] = t;
                s += t; sq += t * t;
            }
            #pragma unroll
            for (int off = 8; off; off >>= 1) {
                s  += __shfl_xor(s, off);
                sq += __shfl_xor(sq, off);
            }
            float mean = s * (1.f / 128.f);
            float var  = sq * (1.f / 128.f) - mean * mean;
            float rstd = rsqrtf(var + 1e-5f);
            if (n < Nn) {
                #pragma unroll
                for (int nt = 0; nt < 8; ++nt) {
                    int col = nt * 16 + l15;
                    float o = (acc[mt][nt][r] - mean) * rstd * gn[col] + bn[col];
                    out[(size_t)n * 128 + col] = o;
                }
            }
        }
}

// ---------------------------------------------------------------------------
extern "C" void kernel_launch(void* const* d_in, const int* in_sizes, int n_in,
                              void* d_out, int out_size, void* d_ws, size_t ws_size,
                              hipStream_t stream) {
    const float* x          = (const float*)d_in[0];
    const float* edge_attr  = (const float*)d_in[1];
    const float* lg_x       = (const float*)d_in[2];
    const float* lg_ea      = (const float*)d_in[3];
    const float* W_line     = (const float*)d_in[4];
    const float* b_line     = (const float*)d_in[5];
    const float* W_gate     = (const float*)d_in[6];
    const float* b_gate     = (const float*)d_in[7];
    const float* W_atom     = (const float*)d_in[8];
    const float* b_atom     = (const float*)d_in[9];
    const float* g_node     = (const float*)d_in[10];
    const float* beta_node  = (const float*)d_in[11];
    const float* g_edge     = (const float*)d_in[12];
    const float* beta_edge  = (const float*)d_in[13];
    const int*   edge_index    = (const int*)d_in[14];
    const int*   lg_edge_index = (const int*)d_in[15];

    const int Nn  = in_sizes[0] / 128;
    const int En  = in_sizes[1] / 128;
    const int LEn = in_sizes[3];

    float* out_x    = (float*)d_out;
    float* out_edge = out_x + (size_t)Nn * 128;
    float* out_lg   = out_edge + (size_t)En * 128;

    const int* lg_src = lg_edge_index;
    const int* lg_dst = lg_edge_index + LEn;
    const int* col    = edge_index + En;

    // ws layout
    short* wp_line = (short*)d_ws;            // 32768 shorts
    short* wp_gate = wp_line + 32768;         // 16384
    short* wp_atom = wp_gate + 16384;         // 32768
    int* ip = (int*)(wp_atom + 32768);
    int* off_lg  = ip;  ip += En + 1;
    int* deg_lg  = ip;  ip += En;             // deg_lg+cur_lg contiguous (1 memset)
    int* cur_lg  = ip;  ip += En;
    int* pos_lg  = ip;  ip += LEn;
    int* bsum_lg = ip;  ip += 1024;
    int* off_at  = ip;  ip += Nn + 1;
    int* deg_at  = ip;  ip += Nn;             // deg_at+cur_at contiguous
    int* cur_at  = ip;  ip += Nn;
    int* pos_at  = ip;  ip += En;
    int* bsum_at = ip;  ip += 1024;
    short* lgx_bf = (short*)(((uintptr_t)ip + 15) & ~(uintptr_t)15);
    short* bufA   = lgx_bf + (size_t)En * 128;       // msg, then gated (256 MB)
    short* agg_bf = bufA + (size_t)En * 128;         // 51 MB
    const size_t need_B = ((uintptr_t)bufA) - (uintptr_t)d_ws;
    const size_t need_A = ((uintptr_t)(agg_bf + (size_t)Nn * 128)) - (uintptr_t)d_ws;
    const bool tierA = ws_size >= need_A;

    hipMemsetAsync(deg_lg, 0, (size_t)En * 8, stream);   // deg_lg + cur_lg
    hipMemsetAsync(deg_at, 0, (size_t)Nn * 8, stream);   // deg_at + cur_at

    k_pack3<<<40, 256, 0, stream>>>(W_line, W_gate, W_atom, wp_line, wp_gate, wp_atom);
    k_cvt<<<2048, 256, 0, stream>>>(lg_x, lgx_bf, (long)En * 16);

    const int nmax = LEn > En ? LEn : En;
    k_hist2<<<(nmax + 255) / 256, 256, 0, stream>>>(lg_dst, deg_lg, LEn, col, deg_at, En);
    const int nb_lg = (En + SCAN_CHUNK - 1) / SCAN_CHUNK;
    const int nb_at = (Nn + SCAN_CHUNK - 1) / SCAN_CHUNK;
    k_scan_block2<<<nb_lg + nb_at, 256, 0, stream>>>(
        deg_lg, En, off_lg, bsum_lg, nb_lg, deg_at, Nn, off_at, bsum_at);
    k_scan_bsum2<<<1, 128, 0, stream>>>(bsum_lg, nb_lg, bsum_at, nb_at);
    const int sa_max = En > Nn ? En : Nn;
    k_scan_add2<<<(sa_max + 255) / 256, 256, 0, stream>>>(
        off_lg, bsum_lg, En, LEn, off_at, bsum_at, Nn, En);
    k_fill_pos2<<<(nmax + 255) / 256, 256, 0, stream>>>(
        lg_dst, off_lg, cur_lg, pos_lg, LEn, col, off_at, cur_at, pos_at, En);

    if (tierA) {
        short* msg = bufA;
        k_line_csr<<<(LEn + 127) / 128, 256, 0, stream>>>(
            lgx_bf, lg_ea, wp_line, W_line, b_line, lg_src, lg_dst, pos_lg, msg, LEn);
        short* enew_bf = lgx_bf;             // safe: same-thread same-index RAW only
        k_lg_edge_fused<<<(En + 7) / 8, 256, 0, stream>>>(
            msg, lgx_bf, edge_attr, off_lg, g_edge, beta_edge,
            out_lg, out_edge, enew_bf, En);
        short* gated = bufA;                 // msg dead after fused gather
        k_gate_csr<true><<<(En + 127) / 128, 256, 0, stream>>>(
            enew_bf, nullptr, wp_gate, b_gate, pos_at, gated, En);
        k_atom_gather<true><<<(Nn + 7) / 8, 256, 0, stream>>>(
            gated, off_at, nullptr, agg_bf, Nn);
        k_atom_mfma<true><<<(Nn + 127) / 128, 256, 0, stream>>>(
            x, nullptr, agg_bf, wp_atom, b_atom, g_node, beta_node, out_x, Nn);
    } else {
        short* msg = (short*)out_edge;       // scratch in d_out, overwritten later
        k_line_csr<<<(LEn + 127) / 128, 256, 0, stream>>>(
            lgx_bf, lg_ea, wp_line, W_line, b_line, lg_src, lg_dst, pos_lg, msg, LEn);
        k_lg_gather<<<(En + 3) / 4, 256, 0, stream>>>(msg, lg_x, off_lg, out_lg, En);
        k_edge_ln<<<(En + 3) / 4, 256, 0, stream>>>(
            out_lg, edge_attr, g_edge, beta_edge, out_edge, En);
        short* gated = lgx_bf;               // lgx_bf dead in tier B here
        k_gate_csr<false><<<(En + 127) / 128, 256, 0, stream>>>(
            nullptr, out_edge, wp_gate, b_gate, pos_at, gated, En);
        k_atom_gather<false><<<(Nn + 7) / 8, 256, 0, stream>>>(
            gated, off_at, out_x, nullptr, Nn);
        k_atom_mfma<false><<<(Nn + 127) / 128, 256, 0, stream>>>(
            x, out_x, nullptr, wp_atom, b_atom, g_node, beta_node, out_x, Nn);
    }
}

// Round 8
// 1449.117 us; speedup vs baseline: 2.0176x; 1.0600x over previous
//
#include <hip/hip_runtime.h>

// ---------------------------------------------------------------------------
// EdgeGatedConv — round 8: CSR-ordered line GEMM + LDS-staged gate epilogue.
//   r7 post-mortem: ~5.3GB traffic vs 840µs floor, at 1536µs. Remaining slack:
//   k_line's random dst-gather + pos-scattered writes, k_gate's scalar global
//   re-reads, launch count.
//   Changes: (1) k_line processes edges in CSR order via perm_lg — dst gather
//   monotone (L2-local), msg writes sequential, no pos scatter. (2) k_gate
//   stages the enew tile in LDS; epilogue reads ev from LDS (in-place
//   overwrite, same thread+address). (3) pack+cvt+hist merged into k_prep.
//   K1 k_line_csr:      GEMM (CSR order) -> msg[p] sequential
//   K2 k_lg_edge_fused: out_lg = bf(lg_x)+mean(msg[o0:o1]); out_edge =
//                       LN(edge_attr+out_lg); enew_bf = bf16(out_edge)
//   K3 k_gate_csr<BF>:  gate=sigmoid(enew@Wg+b); gated row at pos_at[e]
//   K3b k_atom_gather:  agg_bf[n] = sum(gated[o0:o1])
//   K4 k_atom_mfma:     h=silu([x,agg]@Wa+b); out_x = LN(x+h)
// MFMA 16x16x32 bf16: A row=lane&15, B col=lane&15, k=(lane>>4)*8+j both ops;
// C/D col=lane&15, row=(lane>>4)*4+reg.
// ---------------------------------------------------------------------------

typedef __attribute__((ext_vector_type(8))) short s16x8;
typedef __attribute__((ext_vector_type(4))) float f32x4;

#define SCAN_CHUNK 2048

__device__ __forceinline__ short f2bf(float f) {
    unsigned u = __float_as_uint(f);
    u += 0x7FFF + ((u >> 16) & 1);
    return (short)(u >> 16);
}
__device__ __forceinline__ float bf2f(unsigned short h) {
    return __uint_as_float(((unsigned)h) << 16);
}
__device__ __forceinline__ s16x8 pack8(const float* v) {
    s16x8 r;
    #pragma unroll
    for (int j = 0; j < 8; ++j) r[j] = f2bf(v[j]);
    return r;
}

// ---------------- merged prep: pack3 + cvt + hist2 ----------------
__global__ __launch_bounds__(256) void k_prep(
    const float* __restrict__ Wl, const float* __restrict__ Wg,
    const float* __restrict__ Wa,
    short* __restrict__ Pl, short* __restrict__ Pg, short* __restrict__ Pa,
    const float* __restrict__ lgx, short* __restrict__ lgx_bf, long n8,
    const int* __restrict__ idx1, int* __restrict__ deg1, int n1,
    const int* __restrict__ idx2, int* __restrict__ deg2, int n2,
    int cvtBlocks)
{
    const int b = blockIdx.x;
    if (b < 40) {                              // weight pack
        int c = b * 256 + threadIdx.x;
        const float* W; short* P; int cc;
        if (c < 4096)       { W = Wl; P = Pl; cc = c; }
        else if (c < 6144)  { W = Wg; P = Pg; cc = c - 4096; }
        else if (c < 10240) { W = Wa; P = Pa; cc = c - 6144; }
        else return;
        int g = cc >> 7, col = cc & 127, k0 = g * 8;
        s16x8 v;
        #pragma unroll
        for (int j = 0; j < 8; ++j) v[j] = f2bf(W[(size_t)(k0 + j) * 128 + col]);
        ((s16x8*)P)[cc] = v;
    } else if (b < 40 + cvtBlocks) {           // lg_x -> bf16
        long i = (long)(b - 40) * 256 + threadIdx.x;
        const long stride = (long)cvtBlocks * 256;
        for (; i < n8; i += stride) {
            float buf[8];
            *(float4*)&buf[0] = ((const float4*)lgx)[2 * i];
            *(float4*)&buf[4] = ((const float4*)lgx)[2 * i + 1];
            ((s16x8*)lgx_bf)[i] = pack8(buf);
        }
    } else {                                   // dual histogram
        int i = (b - 40 - cvtBlocks) * 256 + threadIdx.x;
        if (i < n1) atomicAdd(&deg1[idx1[i]], 1);
        if (i < n2) atomicAdd(&deg2[idx2[i]], 1);
    }
}

// ---------------- CSR build ----------------
__global__ __launch_bounds__(256) void k_scan_block2(
    const int* __restrict__ in1, int n1, int* __restrict__ out1, int* __restrict__ bsum1, int nb1,
    const int* __restrict__ in2, int n2, int* __restrict__ out2, int* __restrict__ bsum2)
{
    __shared__ int ts[256];
    int b = blockIdx.x;
    const int* in; int n; int* out; int* bsum;
    if (b < nb1) { in = in1; n = n1; out = out1; bsum = bsum1; }
    else         { in = in2; n = n2; out = out2; bsum = bsum2; b -= nb1; }
    const int t = threadIdx.x;
    const int base = b * SCAN_CHUNK + t * 8;
    int v[8]; int s = 0;
    #pragma unroll
    for (int i = 0; i < 8; ++i) { v[i] = (base + i < n) ? in[base + i] : 0; s += v[i]; }
    ts[t] = s;
    __syncthreads();
    int x = s;
    for (int off = 1; off < 256; off <<= 1) {
        int y = (t >= off) ? ts[t - off] : 0;
        __syncthreads();
        x += y; ts[t] = x;
        __syncthreads();
    }
    if (t == 255) bsum[b] = x;
    int run = x - s;
    #pragma unroll
    for (int i = 0; i < 8; ++i) {
        if (base + i < n) out[base + i] = run;
        run += v[i];
    }
}

__global__ void k_scan_bsum2(int* __restrict__ b1, int nb1,
                             int* __restrict__ b2, int nb2) {  // 128 thr = 2 waves
    const int lane = threadIdx.x & 63;
    int* bsum = (threadIdx.x < 64) ? b1 : b2;
    const int nb  = (threadIdx.x < 64) ? nb1 : nb2;
    int carry = 0;
    for (int base = 0; base < nb; base += 64) {
        int i = base + lane;
        int v = (i < nb) ? bsum[i] : 0;
        int inc = v;
        #pragma unroll
        for (int off = 1; off < 64; off <<= 1) {
            int t = __shfl_up(inc, off);
            if (lane >= off) inc += t;
        }
        if (i < nb) bsum[i] = inc - v + carry;
        carry += __shfl(inc, 63);
    }
}

__global__ __launch_bounds__(256) void k_scan_add2(
    int* __restrict__ off1, const int* __restrict__ bsum1, int n1, int ne1,
    int* __restrict__ off2, const int* __restrict__ bsum2, int n2, int ne2)
{
    int i = blockIdx.x * 256 + threadIdx.x;
    if (i < n1) off1[i] += bsum1[i / SCAN_CHUNK];
    if (i < n2) off2[i] += bsum2[i / SCAN_CHUNK];
    if (i == 0) { off1[n1] = ne1; off2[n2] = ne2; }
}

// graph1: perm (pos -> edge); graph2: pos (edge -> pos)
__global__ __launch_bounds__(256) void k_fill2(
    const int* __restrict__ idx1, const int* __restrict__ off1,
    int* __restrict__ cur1, int* __restrict__ perm1, int n1,
    const int* __restrict__ idx2, const int* __restrict__ off2,
    int* __restrict__ cur2, int* __restrict__ pos2, int n2)
{
    int i = blockIdx.x * 256 + threadIdx.x;
    if (i < n1) {
        int s = idx1[i];
        int p = atomicAdd(&cur1[s], 1);
        perm1[off1[s] + p] = i;
    }
    if (i < n2) {
        int s = idx2[i];
        int p = atomicAdd(&cur2[s], 1);
        pos2[i] = off2[s] + p;
    }
}

// ---------------- K1: line GEMM in CSR order -> msg[p] sequential ----------------
__global__ __launch_bounds__(256) void k_line_csr(
    const short* __restrict__ lgx_bf, const float* __restrict__ lg_ea,
    const short* __restrict__ Wp, const float* __restrict__ W_line,
    const float* __restrict__ b_line,
    const int* __restrict__ lg_src, const int* __restrict__ lg_dst,
    const int* __restrict__ perm_lg,
    short* __restrict__ msg, int LEn)
{
    __shared__ __align__(16) short sh[128][136];
    const int tid = threadIdx.x;
    const int ln = tid & 63, wv = tid >> 6;
    const int l15 = ln & 15, lhi = ln >> 4;
    const int pb = blockIdx.x * 128 + wv * 32;
    const s16x8* Bv = (const s16x8*)Wp;

    const short *sp[2], *dp[2];
    int ev_e[2];
    #pragma unroll
    for (int mt = 0; mt < 2; ++mt) {
        int p = pb + mt * 16 + l15;
        int pc = p < LEn ? p : LEn - 1;
        int e = perm_lg[pc];
        ev_e[mt] = e;
        sp[mt] = lgx_bf + (size_t)lg_src[e] * 128;
        dp[mt] = lgx_bf + (size_t)lg_dst[e] * 128;   // monotone in CSR order
    }

    f32x4 acc[2][8];
    #pragma unroll
    for (int m = 0; m < 2; ++m)
        #pragma unroll
        for (int n = 0; n < 8; ++n) acc[m][n] = (f32x4){0.f, 0.f, 0.f, 0.f};

    #pragma unroll 2
    for (int kt = 0; kt < 8; ++kt) {
        int ko = (kt & 3) * 32 + lhi * 8;
        s16x8 a[2];
        #pragma unroll
        for (int mt = 0; mt < 2; ++mt)
            a[mt] = *(const s16x8*)(((kt < 4) ? sp[mt] : dp[mt]) + ko);
        const s16x8* brow = Bv + (size_t)(kt * 4 + lhi) * 128 + l15;
        #pragma unroll
        for (int nt = 0; nt < 8; ++nt) {
            s16x8 b = brow[nt * 16];
            acc[0][nt] = __builtin_amdgcn_mfma_f32_16x16x32_bf16(a[0], b, acc[0][nt], 0, 0, 0);
            acc[1][nt] = __builtin_amdgcn_mfma_f32_16x16x32_bf16(a[1], b, acc[1][nt], 0, 0, 0);
        }
    }

    // per-row lg_ea: C/D rows are lhi*4+r, so fetch via perm of those rows
    float eav[2][4];
    #pragma unroll
    for (int mt = 0; mt < 2; ++mt)
        #pragma unroll
        for (int r = 0; r < 4; ++r) {
            int p = pb + mt * 16 + lhi * 4 + r;
            int pc = p < LEn ? p : LEn - 1;
            eav[mt][r] = lg_ea[perm_lg[pc]];
        }

    #pragma unroll
    for (int nt = 0; nt < 8; ++nt) {
        int col = nt * 16 + l15;
        float wl = W_line[(size_t)256 * 128 + col];
        float bs = b_line[col];
        #pragma unroll
        for (int mt = 0; mt < 2; ++mt)
            #pragma unroll
            for (int r = 0; r < 4; ++r) {
                float v = acc[mt][nt][r] + bs + wl * eav[mt][r];
                float s = v / (1.f + __expf(-v));
                sh[wv * 32 + mt * 16 + lhi * 4 + r][col] = f2bf(s);
            }
    }
    __syncthreads();
    #pragma unroll
    for (int i = 0; i < 8; ++i) {
        int c = tid + i * 256;                 // 128 rows x 16 chunks
        int row = c >> 4, q = c & 15;
        int p = blockIdx.x * 128 + row;
        if (p < LEn)
            *(s16x8*)&msg[(size_t)p * 128 + q * 8] = *(const s16x8*)&sh[row][q * 8];
    }
}

// ---------------- K2: fused gather-mean + residual + edge LN (2 edges/wave) ----------------
__global__ __launch_bounds__(256) void k_lg_edge_fused(
    const short* __restrict__ msg, const short* __restrict__ lgx_bf,
    const float* __restrict__ edge_attr, const int* __restrict__ off,
    const float* __restrict__ g_edge, const float* __restrict__ beta_edge,
    float* __restrict__ out_lg, float* __restrict__ out_edge,
    short* __restrict__ enew_bf, int En)
{
    const int wave = threadIdx.x >> 6, lane = threadIdx.x & 63;
    const int half = lane >> 5, l = lane & 31;
    const int e = blockIdx.x * 8 + wave * 2 + half;
    if (e >= En) return;
    const int o0 = off[e], o1 = off[e + 1];
    const int cnt = o1 - o0;
    const short* mbase = msg + (size_t)o0 * 128 + l * 4;
    float s0 = 0.f, s1 = 0.f, s2 = 0.f, s3 = 0.f;
    for (int j = 0; j < cnt; ++j) {
        ushort4 u = *(const ushort4*)(mbase + (size_t)j * 128);
        s0 += bf2f(u.x); s1 += bf2f(u.y); s2 += bf2f(u.z); s3 += bf2f(u.w);
    }
    const float inv = 1.f / fmaxf((float)cnt, 1.f);
    const size_t rb = (size_t)e * 128 + l * 4;
    ushort4 lxu = *(const ushort4*)&lgx_bf[rb];
    float l0 = fmaf(s0, inv, bf2f(lxu.x));
    float l1 = fmaf(s1, inv, bf2f(lxu.y));
    float l2 = fmaf(s2, inv, bf2f(lxu.z));
    float l3 = fmaf(s3, inv, bf2f(lxu.w));
    *(float4*)&out_lg[rb] = make_float4(l0, l1, l2, l3);

    float4 ea = *(const float4*)&edge_attr[rb];
    float t0 = ea.x + l0, t1 = ea.y + l1, t2 = ea.z + l2, t3 = ea.w + l3;
    float s = t0 + t1 + t2 + t3;
    float sq = t0 * t0 + t1 * t1 + t2 * t2 + t3 * t3;
    #pragma unroll
    for (int o = 16; o; o >>= 1) {             // reduce within 32-lane half
        s  += __shfl_xor(s, o);
        sq += __shfl_xor(sq, o);
    }
    float mean = s * (1.f / 128.f);
    float var  = sq * (1.f / 128.f) - mean * mean;
    float r = rsqrtf(var + 1e-5f);
    int j0 = l * 4;
    float4 gg = *(const float4*)&g_edge[j0];
    float4 bb = *(const float4*)&beta_edge[j0];
    float e0 = fmaf((t0 - mean) * r, gg.x, bb.x);
    float e1 = fmaf((t1 - mean) * r, gg.y, bb.y);
    float e2 = fmaf((t2 - mean) * r, gg.z, bb.z);
    float e3 = fmaf((t3 - mean) * r, gg.w, bb.w);
    *(float4*)&out_edge[rb] = make_float4(e0, e1, e2, e3);
    if (enew_bf) {
        ushort4 ub = make_ushort4((unsigned short)f2bf(e0), (unsigned short)f2bf(e1),
                                  (unsigned short)f2bf(e2), (unsigned short)f2bf(e3));
        *(ushort4*)&enew_bf[rb] = ub;
    }
}

// ---------------- tier-B: unfused gather + LN ----------------
__global__ __launch_bounds__(256) void k_lg_gather(
    const short* __restrict__ msg, const float* __restrict__ lg_x,
    const int* __restrict__ off, float* __restrict__ out_lg, int En)
{
    const int wave = threadIdx.x >> 6, lane = threadIdx.x & 63;
    const int e = blockIdx.x * 4 + wave;
    if (e >= En) return;
    const int o0 = off[e], o1 = off[e + 1];
    const int cnt = o1 - o0;
    const short* base = msg + (size_t)o0 * 128 + lane * 2;
    float s0 = 0.f, s1 = 0.f;
    for (int j = 0; j < cnt; ++j) {
        ushort2 u = *(const ushort2*)(base + (size_t)j * 128);
        s0 += bf2f(u.x); s1 += bf2f(u.y);
    }
    const float inv = 1.f / fmaxf((float)cnt, 1.f);
    const size_t rb = (size_t)e * 128 + lane * 2;
    float2 lx = *(const float2*)&lg_x[rb];
    *(float2*)&out_lg[rb] = make_float2(fmaf(s0, inv, lx.x), fmaf(s1, inv, lx.y));
}

__global__ __launch_bounds__(256) void k_edge_ln(
    const float* __restrict__ lnew, const float* __restrict__ edge_attr,
    const float* __restrict__ g_edge, const float* __restrict__ beta_edge,
    float* __restrict__ out_edge, int En)
{
    const int wave = threadIdx.x >> 6, lane = threadIdx.x & 63;
    const int e = blockIdx.x * 4 + wave;
    if (e >= En) return;
    const size_t rb = (size_t)e * 128 + lane * 2;
    float2 lv = *(const float2*)&lnew[rb];
    float2 ea = *(const float2*)&edge_attr[rb];
    float t0 = ea.x + lv.x, t1 = ea.y + lv.y;
    float s = t0 + t1, sq = t0 * t0 + t1 * t1;
    #pragma unroll
    for (int o = 32; o; o >>= 1) { s += __shfl_xor(s, o); sq += __shfl_xor(sq, o); }
    float mean = s * (1.f / 128.f);
    float var  = sq * (1.f / 128.f) - mean * mean;
    float r = rsqrtf(var + 1e-5f);
    int j0 = lane * 2;
    float o0 = (t0 - mean) * r * g_edge[j0]     + beta_edge[j0];
    float o1 = (t1 - mean) * r * g_edge[j0 + 1] + beta_edge[j0 + 1];
    *(float2*)&out_edge[rb] = make_float2(o0, o1);
}

// ---------------- K3: gate GEMM -> gated row at pos_at[e] ----------------
// BF path: stage enew tile in LDS; epilogue reads ev from LDS and overwrites
// the same element (same thread+address) with the gated value.
template <bool BF>
__global__ __launch_bounds__(256) void k_gate_csr(
    const short* __restrict__ EinB, const float* __restrict__ EinF,
    const short* __restrict__ Wp, const float* __restrict__ bg,
    const int* __restrict__ pos_at, short* __restrict__ gated, int En)
{
    __shared__ __align__(16) short sh[128][136];
    const int tid = threadIdx.x;
    const int ln = tid & 63, wv = tid >> 6;
    const int l15 = ln & 15, lhi = ln >> 4;
    const int eb = blockIdx.x * 128 + wv * 32;
    const s16x8* Bv = (const s16x8*)Wp;

    if (BF) {   // stage the block's 128x128 bf16 enew tile
        #pragma unroll
        for (int i = 0; i < 8; ++i) {
            int c = tid + i * 256;
            int row = c >> 4, q = c & 15;
            int e = blockIdx.x * 128 + row;
            int ec = e < En ? e : En - 1;
            *(s16x8*)&sh[row][q * 8] = *(const s16x8*)&EinB[(size_t)ec * 128 + q * 8];
        }
        __syncthreads();
    }

    int rowi[2];
    #pragma unroll
    for (int mt = 0; mt < 2; ++mt) {
        int e = eb + mt * 16 + l15;
        rowi[mt] = e < En ? e : En - 1;
    }

    f32x4 acc[2][8];
    #pragma unroll
    for (int m = 0; m < 2; ++m)
        #pragma unroll
        for (int n = 0; n < 8; ++n) acc[m][n] = (f32x4){0.f, 0.f, 0.f, 0.f};

    #pragma unroll 2
    for (int kt = 0; kt < 4; ++kt) {
        int ko = kt * 32 + lhi * 8;
        s16x8 a[2];
        #pragma unroll
        for (int mt = 0; mt < 2; ++mt) {
            if (BF) {
                a[mt] = *(const s16x8*)(EinB + (size_t)rowi[mt] * 128 + ko);  // L2-hot
            } else {
                const float* p = EinF + (size_t)rowi[mt] * 128 + ko;
                float buf[8];
                *(float4*)&buf[0] = *(const float4*)p;
                *(float4*)&buf[4] = *(const float4*)(p + 4);
                a[mt] = pack8(buf);
            }
        }
        const s16x8* brow = Bv + (size_t)(kt * 4 + lhi) * 128 + l15;
        #pragma unroll
        for (int nt = 0; nt < 8; ++nt) {
            s16x8 b = brow[nt * 16];
            acc[0][nt] = __builtin_amdgcn_mfma_f32_16x16x32_bf16(a[0], b, acc[0][nt], 0, 0, 0);
            acc[1][nt] = __builtin_amdgcn_mfma_f32_16x16x32_bf16(a[1], b, acc[1][nt], 0, 0, 0);
        }
    }

    #pragma unroll
    for (int nt = 0; nt < 8; ++nt) {
        int col = nt * 16 + l15;
        float bs = bg[col];
        #pragma unroll
        for (int mt = 0; mt < 2; ++mt)
            #pragma unroll
            for (int r = 0; r < 4; ++r) {
                int row = wv * 32 + mt * 16 + lhi * 4 + r;
                int e = eb + mt * 16 + lhi * 4 + r;
                int ec = e < En ? e : En - 1;
                float g = 1.f / (1.f + __expf(-(acc[mt][nt][r] + bs)));
                float ev = BF ? bf2f((unsigned short)sh[row][col])
                              : EinF[(size_t)ec * 128 + col];
                sh[row][col] = f2bf(g * ev);
            }
    }
    __syncthreads();
    #pragma unroll
    for (int i = 0; i < 8; ++i) {
        int c = tid + i * 256;
        int row = c >> 4, q = c & 15;
        int e = blockIdx.x * 128 + row;
        if (e < En) {
            int p = pos_at[e];
            *(s16x8*)&gated[(size_t)p * 128 + q * 8] = *(const s16x8*)&sh[row][q * 8];
        }
    }
}

// ---------------- K3b: contiguous atom aggregation (2 nodes/wave) ----------------
template <bool BF_OUT>
__global__ __launch_bounds__(256) void k_atom_gather(
    const short* __restrict__ gated, const int* __restrict__ off,
    float* __restrict__ aggf, short* __restrict__ aggb, int Nn)
{
    const int wave = threadIdx.x >> 6, lane = threadIdx.x & 63;
    const int half = lane >> 5, l = lane & 31;
    const int n = blockIdx.x * 8 + wave * 2 + half;
    if (n >= Nn) return;
    const int o0 = off[n], o1 = off[n + 1];
    const int cnt = o1 - o0;
    const short* base = gated + (size_t)o0 * 128 + l * 4;
    float s0 = 0.f, s1 = 0.f, s2 = 0.f, s3 = 0.f;
    for (int j = 0; j < cnt; ++j) {
        ushort4 u = *(const ushort4*)(base + (size_t)j * 128);
        s0 += bf2f(u.x); s1 += bf2f(u.y); s2 += bf2f(u.z); s3 += bf2f(u.w);
    }
    const size_t rb = (size_t)n * 128 + l * 4;
    if (BF_OUT) {
        ushort4 ub = make_ushort4((unsigned short)f2bf(s0), (unsigned short)f2bf(s1),
                                  (unsigned short)f2bf(s2), (unsigned short)f2bf(s3));
        *(ushort4*)&aggb[rb] = ub;
    } else {
        *(float4*)&aggf[rb] = make_float4(s0, s1, s2, s3);
    }
}

// ---------------- K4: atom GEMM + residual + in-register LN ----------------
template <bool AGGBF>
__global__ __launch_bounds__(256) void k_atom_mfma(
    const float* __restrict__ x, const float* __restrict__ aggf,
    const short* __restrict__ aggb,
    const short* __restrict__ Wp, const float* __restrict__ ba,
    const float* __restrict__ gn, const float* __restrict__ bn,
    float* __restrict__ out, int Nn)
{
    const int tid = threadIdx.x;
    const int ln = tid & 63, wv = tid >> 6;
    const int l15 = ln & 15, lhi = ln >> 4;
    const int nb = blockIdx.x * 128 + wv * 32;
    const s16x8* Bv = (const s16x8*)Wp;

    const float* xp[2];
    size_t nc[2];
    #pragma unroll
    for (int mt = 0; mt < 2; ++mt) {
        int n = nb + mt * 16 + l15;
        nc[mt] = (size_t)(n < Nn ? n : Nn - 1) * 128;
        xp[mt] = x + nc[mt];
    }

    f32x4 acc[2][8];
    #pragma unroll
    for (int m = 0; m < 2; ++m)
        #pragma unroll
        for (int n = 0; n < 8; ++n) acc[m][n] = (f32x4){0.f, 0.f, 0.f, 0.f};

    #pragma unroll 2
    for (int kt = 0; kt < 8; ++kt) {
        int ko = (kt & 3) * 32 + lhi * 8;
        s16x8 a[2];
        #pragma unroll
        for (int mt = 0; mt < 2; ++mt) {
            if (kt < 4) {
                const float* p = xp[mt] + ko;
                float buf[8];
                *(float4*)&buf[0] = *(const float4*)p;
                *(float4*)&buf[4] = *(const float4*)(p + 4);
                a[mt] = pack8(buf);
            } else if (AGGBF) {
                a[mt] = *(const s16x8*)(aggb + nc[mt] + ko);
            } else {
                const float* p = aggf + nc[mt] + ko;
                float buf[8];
                *(float4*)&buf[0] = *(const float4*)p;
                *(float4*)&buf[4] = *(const float4*)(p + 4);
                a[mt] = pack8(buf);
            }
        }
        const s16x8* brow = Bv + (size_t)(kt * 4 + lhi) * 128 + l15;
        #pragma unroll
        for (int nt = 0; nt < 8; ++nt) {
            s16x8 b = brow[nt * 16];
            acc[0][nt] = __builtin_amdgcn_mfma_f32_16x16x32_bf16(a[0], b, acc[0][nt], 0, 0, 0);
            acc[1][nt] = __builtin_amdgcn_mfma_f32_16x16x32_bf16(a[1], b, acc[1][nt], 0, 0, 0);
        }
    }

    #pragma unroll
    for (int mt = 0; mt < 2; ++mt)
        #pragma unroll
        for (int r = 0; r < 4; ++r) {
            int n = nb + mt * 16 + lhi * 4 + r;
            size_t nr = (size_t)(n < Nn ? n : 0) * 128;
            float s = 0.f, sq = 0.f;
            #pragma unroll
            for (int nt = 0; nt < 8; ++nt) {
                int col = nt * 16 + l15;
                float v = acc[mt][nt][r] + ba[col];
                float h = v / (1.f + __expf(-v));
                float t = x[nr + col] + h;
                acc[mt][nt][r] = t;
                s += t; sq += t * t;
            }
            #pragma unroll
            for (int off = 8; off; off >>= 1) {
                s  += __shfl_xor(s, off);
                sq += __shfl_xor(sq, off);
            }
            float mean = s * (1.f / 128.f);
            float var  = sq * (1.f / 128.f) - mean * mean;
            float rstd = rsqrtf(var + 1e-5f);
            if (n < Nn) {
                #pragma unroll
                for (int nt = 0; nt < 8; ++nt) {
                    int col = nt * 16 + l15;
                    float o = (acc[mt][nt][r] - mean) * rstd * gn[col] + bn[col];
                    out[(size_t)n * 128 + col] = o;
                }
            }
        }
}

// ---------------------------------------------------------------------------
extern "C" void kernel_launch(void* const* d_in, const int* in_sizes, int n_in,
                              void* d_out, int out_size, void* d_ws, size_t ws_size,
                              hipStream_t stream) {
    const float* x          = (const float*)d_in[0];
    const float* edge_attr  = (const float*)d_in[1];
    const float* lg_x       = (const float*)d_in[2];
    const float* lg_ea      = (const float*)d_in[3];
    const float* W_line     = (const float*)d_in[4];
    const float* b_line     = (const float*)d_in[5];
    const float* W_gate     = (const float*)d_in[6];
    const float* b_gate     = (const float*)d_in[7];
    const float* W_atom     = (const float*)d_in[8];
    const float* b_atom     = (const float*)d_in[9];
    const float* g_node     = (const float*)d_in[10];
    const float* beta_node  = (const float*)d_in[11];
    const float* g_edge     = (const float*)d_in[12];
    const float* beta_edge  = (const float*)d_in[13];
    const int*   edge_index    = (const int*)d_in[14];
    const int*   lg_edge_index = (const int*)d_in[15];

    const int Nn  = in_sizes[0] / 128;
    const int En  = in_sizes[1] / 128;
    const int LEn = in_sizes[3];

    float* out_x    = (float*)d_out;
    float* out_edge = out_x + (size_t)Nn * 128;
    float* out_lg   = out_edge + (size_t)En * 128;

    const int* lg_src = lg_edge_index;
    const int* lg_dst = lg_edge_index + LEn;
    const int* col    = edge_index + En;

    // ws layout
    short* wp_line = (short*)d_ws;            // 32768 shorts
    short* wp_gate = wp_line + 32768;         // 16384
    short* wp_atom = wp_gate + 16384;         // 32768
    int* ip = (int*)(wp_atom + 32768);
    int* off_lg  = ip;  ip += En + 1;
    int* deg_lg  = ip;  ip += En;             // deg_lg+cur_lg contiguous (1 memset)
    int* cur_lg  = ip;  ip += En;
    int* perm_lg = ip;  ip += LEn;
    int* bsum_lg = ip;  ip += 1024;
    int* off_at  = ip;  ip += Nn + 1;
    int* deg_at  = ip;  ip += Nn;             // deg_at+cur_at contiguous
    int* cur_at  = ip;  ip += Nn;
    int* pos_at  = ip;  ip += En;
    int* bsum_at = ip;  ip += 1024;
    short* lgx_bf = (short*)(((uintptr_t)ip + 15) & ~(uintptr_t)15);
    short* bufA   = lgx_bf + (size_t)En * 128;       // msg, then gated (256 MB)
    short* agg_bf = bufA + (size_t)En * 128;         // 51 MB
    const size_t need_A = ((uintptr_t)(agg_bf + (size_t)Nn * 128)) - (uintptr_t)d_ws;
    const bool tierA = ws_size >= need_A;

    hipMemsetAsync(deg_lg, 0, (size_t)En * 8, stream);   // deg_lg + cur_lg
    hipMemsetAsync(deg_at, 0, (size_t)Nn * 8, stream);   // deg_at + cur_at

    const int nmax = LEn > En ? LEn : En;
    const int cvtBlocks = 2048;
    const int histBlocks = (nmax + 255) / 256;
    k_prep<<<40 + cvtBlocks + histBlocks, 256, 0, stream>>>(
        W_line, W_gate, W_atom, wp_line, wp_gate, wp_atom,
        lg_x, lgx_bf, (long)En * 16,
        lg_dst, deg_lg, LEn, col, deg_at, En, cvtBlocks);

    const int nb_lg = (En + SCAN_CHUNK - 1) / SCAN_CHUNK;
    const int nb_at = (Nn + SCAN_CHUNK - 1) / SCAN_CHUNK;
    k_scan_block2<<<nb_lg + nb_at, 256, 0, stream>>>(
        deg_lg, En, off_lg, bsum_lg, nb_lg, deg_at, Nn, off_at, bsum_at);
    k_scan_bsum2<<<1, 128, 0, stream>>>(bsum_lg, nb_lg, bsum_at, nb_at);
    const int sa_max = En > Nn ? En : Nn;
    k_scan_add2<<<(sa_max + 255) / 256, 256, 0, stream>>>(
        off_lg, bsum_lg, En, LEn, off_at, bsum_at, Nn, En);
    k_fill2<<<(nmax + 255) / 256, 256, 0, stream>>>(
        lg_dst, off_lg, cur_lg, perm_lg, LEn, col, off_at, cur_at, pos_at, En);

    if (tierA) {
        short* msg = bufA;
        k_line_csr<<<(LEn + 127) / 128, 256, 0, stream>>>(
            lgx_bf, lg_ea, wp_line, W_line, b_line, lg_src, lg_dst, perm_lg, msg, LEn);
        short* enew_bf = lgx_bf;             // safe: same-thread same-index RAW only
        k_lg_edge_fused<<<(En + 7) / 8, 256, 0, stream>>>(
            msg, lgx_bf, edge_attr, off_lg, g_edge, beta_edge,
            out_lg, out_edge, enew_bf, En);
        short* gated = bufA;                 // msg dead after fused gather
        k_gate_csr<true><<<(En + 127) / 128, 256, 0, stream>>>(
            enew_bf, nullptr, wp_gate, b_gate, pos_at, gated, En);
        k_atom_gather<true><<<(Nn + 7) / 8, 256, 0, stream>>>(
            gated, off_at, nullptr, agg_bf, Nn);
        k_atom_mfma<true><<<(Nn + 127) / 128, 256, 0, stream>>>(
            x, nullptr, agg_bf, wp_atom, b_atom, g_node, beta_node, out_x, Nn);
    } else {
        short* msg = (short*)out_edge;       // scratch in d_out, overwritten later
        k_line_csr<<<(LEn + 127) / 128, 256, 0, stream>>>(
            lgx_bf, lg_ea, wp_line, W_line, b_line, lg_src, lg_dst, perm_lg, msg, LEn);
        k_lg_gather<<<(En + 3) / 4, 256, 0, stream>>>(msg, lg_x, off_lg, out_lg, En);
        k_edge_ln<<<(En + 3) / 4, 256, 0, stream>>>(
            out_lg, edge_attr, g_edge, beta_edge, out_edge, En);
        short* gated = lgx_bf;               // lgx_bf dead in tier B here
        k_gate_csr<false><<<(En + 127) / 128, 256, 0, stream>>>(
            nullptr, out_edge, wp_gate, b_gate, pos_at, gated, En);
        k_atom_gather<false><<<(Nn + 7) / 8, 256, 0, stream>>>(
            gated, off_at, out_x, nullptr, Nn);
        k_atom_mfma<false><<<(Nn + 127) / 128, 256, 0, stream>>>(
            x, out_x, nullptr, wp_atom, b_atom, g_node, beta_node, out_x, Nn);
    }
}